// Round 1
// baseline (3841.196 us; speedup 1.0000x reference)
//
#include <hip/hip_runtime.h>
#include <cstddef>

#define EPS 1e-5f

// ---------------- init: zero degree counts + stats area ----------------
__global__ void k_init(int* __restrict__ deg, float* __restrict__ stats, int n) {
    int i = blockIdx.x * blockDim.x + threadIdx.x;
    if (i < n) deg[i] = 0;
    if (i < 256) stats[i] = 0.f;   // 4 layers x (S1[16]+S2[16]) = 128 floats, maxbuf at [128..135]
}

// ---------------- degree count ----------------
__global__ void k_count(const int* __restrict__ dst, int* __restrict__ deg, int E) {
    int e = blockIdx.x * blockDim.x + threadIdx.x;
    if (e < E) atomicAdd(&deg[dst[e]], 1);
}

__global__ void k_dinv(const int* __restrict__ deg, float* __restrict__ dinv, int n) {
    int i = blockIdx.x * blockDim.x + threadIdx.x;
    if (i < n) dinv[i] = rsqrtf((float)(deg[i] + 1));   // +1 self loop; always > 0
}

// ---------------- layer 1 linear: 128 -> 8, LDS-tiled ----------------
// hs[i][j] = (x[i] @ W)[j] * dinv[i]; acc initialized to hs (self-loop term)
#define TN 64
__global__ void k_lin1(const float* __restrict__ x, const float* __restrict__ W,
                       const float* __restrict__ dinv,
                       float* __restrict__ hs, float* __restrict__ acc, int n) {
    __shared__ float xs[TN * 132];   // row stride 132 floats: bank-conflict-free (132%32=4)
    __shared__ float ws[128 * 8];
    int tid = threadIdx.x;
    int base = blockIdx.x * TN;
    for (int i = tid; i < 1024; i += 256) ws[i] = W[i];
    int nvalid = n - base; if (nvalid > TN) nvalid = TN;
    int limit4 = nvalid * 32;  // float4 per row = 32
    const float4* x4 = (const float4*)(x + (size_t)base * 128);
    float4* xs4 = (float4*)xs;
    for (int i = tid; i < TN * 32; i += 256) {
        if (i < limit4) {
            int row = i >> 5, col = i & 31;
            xs4[row * 33 + col] = x4[i];
        }
    }
    __syncthreads();
    #pragma unroll
    for (int rep = 0; rep < 2; ++rep) {
        int o = rep * 256 + tid;         // 0..511 = 64 nodes x 8 feats
        int node = o >> 3, feat = o & 7;
        if (node < nvalid) {
            const float* xr = xs + node * 132;
            float s = 0.f;
            #pragma unroll 8
            for (int k = 0; k < 128; ++k) s = fmaf(xr[k], ws[k * 8 + feat], s);
            s *= dinv[base + node];
            size_t idx = (size_t)(base + node) * 8 + feat;
            hs[idx] = s;
            acc[idx] = s;
        }
    }
}

// ---------------- small linears: FIN -> FOUT, thread per node ----------------
template<int FIN, int FOUT>
__global__ void k_lin(const float* __restrict__ x, const float* __restrict__ W,
                      const float* __restrict__ dinv,
                      float* __restrict__ hs, float* __restrict__ acc, int n) {
    __shared__ float ws[FIN * FOUT];
    int tid = threadIdx.x;
    for (int i = tid; i < FIN * FOUT; i += blockDim.x) ws[i] = W[i];
    __syncthreads();
    int i = blockIdx.x * blockDim.x + tid;
    if (i >= n) return;
    float xr[FIN];
    const float4* xp = (const float4*)(x + (size_t)i * FIN);
    #pragma unroll
    for (int q = 0; q < FIN / 4; ++q) {
        float4 v = xp[q];
        xr[4*q+0] = v.x; xr[4*q+1] = v.y; xr[4*q+2] = v.z; xr[4*q+3] = v.w;
    }
    float di = dinv[i];
    float out[FOUT];
    #pragma unroll
    for (int j = 0; j < FOUT; ++j) {
        float s = 0.f;
        #pragma unroll
        for (int k = 0; k < FIN; ++k) s = fmaf(xr[k], ws[k * FOUT + j], s);
        out[j] = s * di;
    }
    float4* hp = (float4*)(hs + (size_t)i * FOUT);
    float4* ap = (float4*)(acc + (size_t)i * FOUT);
    #pragma unroll
    for (int q = 0; q < FOUT / 4; ++q) {
        float4 v; v.x = out[4*q+0]; v.y = out[4*q+1]; v.z = out[4*q+2]; v.w = out[4*q+3];
        hp[q] = v; ap[q] = v;
    }
}

// ---------------- edge scatter: acc[dst] += hs[src] ----------------
template<int F>
__global__ void k_scatter(const int* __restrict__ src, const int* __restrict__ dst,
                          const float* __restrict__ hs, float* __restrict__ acc, int E) {
    constexpr int P = F / 4;                   // float4 parts per row
    constexpr int SHIFT = (P == 2) ? 1 : 2;
    int t = blockIdx.x * blockDim.x + threadIdx.x;
    int e = t >> SHIFT;
    int part = t & (P - 1);
    if (e >= E) return;
    int s = src[e], d = dst[e];
    float4 v = *(const float4*)(hs + (size_t)s * F + 4 * part);
    float* a = acc + (size_t)d * F + 4 * part;
    atomicAdd(a + 0, v.x);
    atomicAdd(a + 1, v.y);
    atomicAdd(a + 2, v.z);
    atomicAdd(a + 3, v.w);
}

// ---------------- per-feature sum / sumsq of v = dinv[i]*acc[i][j] ----------------
template<int F>
__global__ void k_reduce(const float* __restrict__ acc, const float* __restrict__ dinv,
                         float* __restrict__ S, int n) {
    float s1[F], s2[F];
    #pragma unroll
    for (int j = 0; j < F; ++j) { s1[j] = 0.f; s2[j] = 0.f; }
    int stride = gridDim.x * blockDim.x;
    for (int i = blockIdx.x * blockDim.x + threadIdx.x; i < n; i += stride) {
        float di = dinv[i];
        const float4* ap = (const float4*)(acc + (size_t)i * F);
        #pragma unroll
        for (int q = 0; q < F / 4; ++q) {
            float4 a = ap[q];
            float v;
            v = a.x * di; s1[4*q+0] += v; s2[4*q+0] += v * v;
            v = a.y * di; s1[4*q+1] += v; s2[4*q+1] += v * v;
            v = a.z * di; s1[4*q+2] += v; s2[4*q+2] += v * v;
            v = a.w * di; s1[4*q+3] += v; s2[4*q+3] += v * v;
        }
    }
    #pragma unroll
    for (int j = 0; j < F; ++j) {
        for (int off = 32; off > 0; off >>= 1) {
            s1[j] += __shfl_down(s1[j], off);
            s2[j] += __shfl_down(s2[j], off);
        }
    }
    if ((threadIdx.x & 63) == 0) {
        #pragma unroll
        for (int j = 0; j < F; ++j) {
            atomicAdd(&S[j], s1[j]);
            atomicAdd(&S[F + j], s2[j]);
        }
    }
}

// ---------------- BN + ReLU apply (optionally fused max-pool) ----------------
// o = dinv[i]*acc[i][j] + b[j]; BN subtracts the mean so b cancels exactly.
template<int F, bool DOMAX>
__global__ void k_bn(const float* __restrict__ acc, const float* __restrict__ dinv,
                     const float* __restrict__ S,
                     const float* __restrict__ g, const float* __restrict__ be,
                     float* __restrict__ outb, float* __restrict__ maxbuf, int n) {
    __shared__ float sc[F], sh[F];
    int tid = threadIdx.x;
    if (tid < F) {
        float mu = S[tid] / (float)n;
        float var = S[F + tid] / (float)n - mu * mu;
        float inv = rsqrtf(var + EPS) * g[tid];
        sc[tid] = inv;
        sh[tid] = be[tid] - mu * inv;
    }
    __syncthreads();
    int i = blockIdx.x * blockDim.x + tid;
    float vals[F];
    #pragma unroll
    for (int j = 0; j < F; ++j) vals[j] = 0.f;
    if (i < n) {
        float di = dinv[i];
        const float4* ap = (const float4*)(acc + (size_t)i * F);
        float4* op = (float4*)(outb + (size_t)i * F);
        #pragma unroll
        for (int q = 0; q < F / 4; ++q) {
            float4 a = ap[q];
            float4 o;
            o.x = fmaxf(fmaf(a.x * di, sc[4*q+0], sh[4*q+0]), 0.f);
            o.y = fmaxf(fmaf(a.y * di, sc[4*q+1], sh[4*q+1]), 0.f);
            o.z = fmaxf(fmaf(a.z * di, sc[4*q+2], sh[4*q+2]), 0.f);
            o.w = fmaxf(fmaf(a.w * di, sc[4*q+3], sh[4*q+3]), 0.f);
            op[q] = o;
            if (DOMAX) {
                vals[4*q+0] = o.x; vals[4*q+1] = o.y; vals[4*q+2] = o.z; vals[4*q+3] = o.w;
            }
        }
    }
    if (DOMAX) {
        #pragma unroll
        for (int j = 0; j < F; ++j) {
            for (int off = 32; off > 0; off >>= 1)
                vals[j] = fmaxf(vals[j], __shfl_down(vals[j], off));
        }
        if ((tid & 63) == 0) {
            #pragma unroll
            for (int j = 0; j < F; ++j)
                atomicMax((unsigned int*)&maxbuf[j], __float_as_uint(vals[j]));  // vals >= 0
        }
    }
}

// ---------------- final: out = max_pooled . Wout + bout ----------------
__global__ void k_final(const float* __restrict__ maxbuf, const float* __restrict__ Wout,
                        const float* __restrict__ bout, float* __restrict__ out) {
    if (threadIdx.x == 0) {
        float s = bout[0];
        #pragma unroll
        for (int j = 0; j < 8; ++j) s = fmaf(maxbuf[j], Wout[j], s);
        out[0] = s;
    }
}

extern "C" void kernel_launch(void* const* d_in, const int* in_sizes, int n_in,
                              void* d_out, int out_size, void* d_ws, size_t ws_size,
                              hipStream_t stream) {
    const float* x    = (const float*)d_in[0];
    const int*   ei   = (const int*)d_in[1];
    const float* W1   = (const float*)d_in[2];
    const float* g1   = (const float*)d_in[4];
    const float* be1  = (const float*)d_in[5];
    const float* W2   = (const float*)d_in[6];
    const float* g2   = (const float*)d_in[8];
    const float* be2  = (const float*)d_in[9];
    const float* W3   = (const float*)d_in[10];
    const float* g3   = (const float*)d_in[12];
    const float* be3  = (const float*)d_in[13];
    const float* W4   = (const float*)d_in[14];
    const float* g4   = (const float*)d_in[16];
    const float* be4  = (const float*)d_in[17];
    const float* Wout = (const float*)d_in[18];
    const float* bout = (const float*)d_in[19];
    float* out = (float*)d_out;

    const int N = in_sizes[0] / 128;
    const int E = in_sizes[1] / 2;
    const int* src = ei;
    const int* dst = ei + E;

    // workspace layout (bytes)
    char* ws = (char*)d_ws;
    int*   deg   = (int*)(ws);                          // 4N
    float* dinv  = (float*)(ws + (size_t)4 * N);        // 4N
    float* stats = (float*)(ws + (size_t)8 * N);        // 1KB (S arrays + maxbuf)
    float* hs    = (float*)(ws + (size_t)8 * N + 4096); // 64N
    float* acc   = (float*)(ws + (size_t)8 * N + 4096 + (size_t)64 * N);  // 64N
    float* xbuf  = (float*)(ws + (size_t)8 * N + 4096 + (size_t)128 * N); // 64N
    float* maxbuf = stats + 128;

    const int B = 256;
    int gN  = (N + B - 1) / B;
    int gE  = (E + B - 1) / B;
    int gE2 = (2 * E + B - 1) / B;
    int gE4 = (4 * E + B - 1) / B;

    // degree / dinv (shared across layers)
    k_init<<<gN + 1, B, 0, stream>>>(deg, stats, N);
    k_count<<<gE, B, 0, stream>>>(dst, deg, E);
    k_dinv<<<gN, B, 0, stream>>>(deg, dinv, N);

    // ---- layer 1: 128 -> 8 ----
    k_lin1<<<(N + TN - 1) / TN, B, 0, stream>>>(x, W1, dinv, hs, acc, N);
    k_scatter<8><<<gE2, B, 0, stream>>>(src, dst, hs, acc, E);
    k_reduce<8><<<256, B, 0, stream>>>(acc, dinv, stats + 0, N);
    k_bn<8, false><<<gN, B, 0, stream>>>(acc, dinv, stats + 0, g1, be1, xbuf, nullptr, N);

    // ---- layer 2: 8 -> 16 ----
    k_lin<8, 16><<<gN, B, 0, stream>>>(xbuf, W2, dinv, hs, acc, N);
    k_scatter<16><<<gE4, B, 0, stream>>>(src, dst, hs, acc, E);
    k_reduce<16><<<256, B, 0, stream>>>(acc, dinv, stats + 32, N);
    k_bn<16, false><<<gN, B, 0, stream>>>(acc, dinv, stats + 32, g2, be2, xbuf, nullptr, N);

    // ---- layer 3: 16 -> 16 ----
    k_lin<16, 16><<<gN, B, 0, stream>>>(xbuf, W3, dinv, hs, acc, N);
    k_scatter<16><<<gE4, B, 0, stream>>>(src, dst, hs, acc, E);
    k_reduce<16><<<256, B, 0, stream>>>(acc, dinv, stats + 64, N);
    k_bn<16, false><<<gN, B, 0, stream>>>(acc, dinv, stats + 64, g3, be3, xbuf, nullptr, N);

    // ---- layer 4: 16 -> 8 (fused max-pool) ----
    k_lin<16, 8><<<gN, B, 0, stream>>>(xbuf, W4, dinv, hs, acc, N);
    k_scatter<8><<<gE2, B, 0, stream>>>(src, dst, hs, acc, E);
    k_reduce<8><<<256, B, 0, stream>>>(acc, dinv, stats + 96, N);
    k_bn<8, true><<<gN, B, 0, stream>>>(acc, dinv, stats + 96, g4, be4, xbuf, maxbuf, N);

    k_final<<<1, 64, 0, stream>>>(maxbuf, Wout, bout, out);
}

// Round 2
// 935.225 us; speedup vs baseline: 4.1072x; 4.1072x over previous
//
#include <hip/hip_runtime.h>
#include <cstddef>

#define EPS 1e-5f

// ---------------- init: zero degree counts + stats area ----------------
__global__ void k_init(int* __restrict__ deg, float* __restrict__ stats, int n) {
    int i = blockIdx.x * blockDim.x + threadIdx.x;
    if (i < n) deg[i] = 0;
    if (i < 256) stats[i] = 0.f;   // 4 layers x (S1+S2) blocks of 32 floats; maxbuf at [128..135]
}

// ---------------- degree count (in-degree over dst) ----------------
__global__ void k_count(const int* __restrict__ dst, int* __restrict__ deg, int E) {
    int e = blockIdx.x * blockDim.x + threadIdx.x;
    if (e < E) atomicAdd(&deg[dst[e]], 1);
}

__global__ void k_dinv(const int* __restrict__ deg, float* __restrict__ dinv, int n) {
    int i = blockIdx.x * blockDim.x + threadIdx.x;
    if (i < n) dinv[i] = rsqrtf((float)(deg[i] + 1));   // +1 self loop; always > 0
}

// ---------------- prefix scan (3-stage, block=256) ----------------
__global__ void k_scan_a(const int* __restrict__ deg, int* __restrict__ rloc,
                         int* __restrict__ bsum, int n) {
    int i = blockIdx.x * 256 + threadIdx.x;
    int v = (i < n) ? deg[i] : 0;
    int lane = threadIdx.x & 63;
    int wid = threadIdx.x >> 6;
    int x = v;
    #pragma unroll
    for (int off = 1; off < 64; off <<= 1) {
        int y = __shfl_up(x, off);
        if (lane >= off) x += y;
    }
    __shared__ int wsum[4];
    if (lane == 63) wsum[wid] = x;
    __syncthreads();
    int add = 0;
    for (int w = 0; w < wid; ++w) add += wsum[w];
    int incl = x + add;
    if (i < n) rloc[i] = incl - v;            // exclusive within block
    if (threadIdx.x == 255) bsum[blockIdx.x] = incl;  // block total
}

__global__ void k_scan_b(int* __restrict__ bsum, int nb) {   // single block of 512
    __shared__ int tmp[512];
    int t = threadIdx.x;
    int v = (t < nb) ? bsum[t] : 0;
    tmp[t] = v;
    __syncthreads();
    for (int off = 1; off < 512; off <<= 1) {
        int y = (t >= off) ? tmp[t - off] : 0;
        __syncthreads();
        tmp[t] += y;
        __syncthreads();
    }
    if (t < nb) bsum[t] = tmp[t] - v;          // exclusive over blocks
}

__global__ void k_scan_c(const int* __restrict__ rloc, const int* __restrict__ bsum,
                         int* __restrict__ row_start, int* __restrict__ cursor,
                         int n, int E) {
    int i = blockIdx.x * 256 + threadIdx.x;
    if (i < n) {
        int v = rloc[i] + bsum[blockIdx.x];
        row_start[i] = v;
        cursor[i] = v;
        if (i == n - 1) row_start[n] = E;
    }
}

// ---------------- counting-sort fill: csr_src grouped by dst ----------------
__global__ void k_fill(const int* __restrict__ dst, const int* __restrict__ src,
                       int* __restrict__ cursor, int* __restrict__ csr_src, int E) {
    int e = blockIdx.x * blockDim.x + threadIdx.x;
    if (e < E) {
        int d = dst[e];
        int p = atomicAdd(&cursor[d], 1);
        csr_src[p] = src[e];
    }
}

// ---------------- layer 1 linear: 128 -> 8, LDS-tiled ----------------
// hs[i][j] = (x[i] @ W)[j] * dinv[i]
#define TN 64
__global__ void k_lin1(const float* __restrict__ x, const float* __restrict__ W,
                       const float* __restrict__ dinv,
                       float* __restrict__ hs, int n) {
    __shared__ float xs[TN * 132];   // row stride 132 floats (132%32=4): conflict-free
    __shared__ float ws[128 * 8];
    int tid = threadIdx.x;
    int base = blockIdx.x * TN;
    for (int i = tid; i < 1024; i += 256) ws[i] = W[i];
    int nvalid = n - base; if (nvalid > TN) nvalid = TN;
    int limit4 = nvalid * 32;
    const float4* x4 = (const float4*)(x + (size_t)base * 128);
    float4* xs4 = (float4*)xs;
    for (int i = tid; i < TN * 32; i += 256) {
        if (i < limit4) {
            int row = i >> 5, col = i & 31;
            xs4[row * 33 + col] = x4[i];
        }
    }
    __syncthreads();
    #pragma unroll
    for (int rep = 0; rep < 2; ++rep) {
        int o = rep * 256 + tid;         // 64 nodes x 8 feats
        int node = o >> 3, feat = o & 7;
        if (node < nvalid) {
            const float* xr = xs + node * 132;
            float s = 0.f;
            #pragma unroll 8
            for (int k = 0; k < 128; ++k) s = fmaf(xr[k], ws[k * 8 + feat], s);
            s *= dinv[base + node];
            hs[(size_t)(base + node) * 8 + feat] = s;
        }
    }
}

// ---------------- CSR gather + fused BN-stats ----------------
// acc[d] = hs[d] + sum_{s in in(d)} hs[s];  stats on v = acc*dinv[d]
template<int F>
__global__ void k_gather(const int* __restrict__ row_start, const int* __restrict__ csr_src,
                         const float* __restrict__ hs, const float* __restrict__ dinv,
                         float* __restrict__ acc, float* __restrict__ S, int n) {
    constexpr int P = F / 4;                  // float4 parts (threads) per node
    constexpr int SHIFT = (P == 2) ? 1 : 2;
    __shared__ float ls[2 * F];
    if (threadIdx.x < 2 * F) ls[threadIdx.x] = 0.f;
    __syncthreads();

    int t = blockIdx.x * blockDim.x + threadIdx.x;
    int node = t >> SHIFT;
    int part = t & (P - 1);
    int lane = threadIdx.x & 63;

    float4 a = make_float4(0.f, 0.f, 0.f, 0.f);
    float di = 0.f;
    if (node < n) {
        const float4* hp = (const float4*)hs;
        a = hp[(size_t)node * P + part];      // self-loop term
        int e = row_start[node], end = row_start[node + 1];
        int s_next = (e < end) ? csr_src[e] : 0;
        while (e < end) {
            int s = s_next;
            ++e;
            if (e < end) s_next = csr_src[e]; // prefetch next index
            float4 v = hp[(size_t)s * P + part];
            a.x += v.x; a.y += v.y; a.z += v.z; a.w += v.w;
        }
        ((float4*)acc)[(size_t)node * P + part] = a;
        di = dinv[node];
    }
    // v = a * dinv[node]  (zeros for padding threads)
    float vx = a.x * di, vy = a.y * di, vz = a.z * di, vw = a.w * di;
    float s1x = vx, s1y = vy, s1z = vz, s1w = vw;
    float s2x = vx * vx, s2y = vy * vy, s2z = vz * vz, s2w = vw * vw;
    #pragma unroll
    for (int off = P; off < 64; off <<= 1) {
        s1x += __shfl_down(s1x, off); s1y += __shfl_down(s1y, off);
        s1z += __shfl_down(s1z, off); s1w += __shfl_down(s1w, off);
        s2x += __shfl_down(s2x, off); s2y += __shfl_down(s2y, off);
        s2z += __shfl_down(s2z, off); s2w += __shfl_down(s2w, off);
    }
    if (lane < P) {
        int j = part * 4;
        atomicAdd(&ls[j + 0], s1x); atomicAdd(&ls[j + 1], s1y);
        atomicAdd(&ls[j + 2], s1z); atomicAdd(&ls[j + 3], s1w);
        atomicAdd(&ls[F + j + 0], s2x); atomicAdd(&ls[F + j + 1], s2y);
        atomicAdd(&ls[F + j + 2], s2z); atomicAdd(&ls[F + j + 3], s2w);
    }
    __syncthreads();
    if (threadIdx.x < 2 * F) atomicAdd(&S[threadIdx.x], ls[threadIdx.x]);
}

// ---------------- fused BN + ReLU + next linear ----------------
// in: acc (FIN), stats S; out: hs_next[i][j] = relu(bn(acc[i]*dinv[i])) @ W * dinv[i]
template<int FIN, int FOUT>
__global__ void k_bnlin(const float* __restrict__ acc, const float* __restrict__ dinv,
                        const float* __restrict__ S,
                        const float* __restrict__ g, const float* __restrict__ be,
                        const float* __restrict__ W,
                        float* __restrict__ hs, int n) {
    __shared__ float sc[FIN], sh[FIN], ws[FIN * FOUT];
    int tid = threadIdx.x;
    if (tid < FIN) {
        float mu = S[tid] / (float)n;
        float var = S[FIN + tid] / (float)n - mu * mu;
        float inv = rsqrtf(var + EPS) * g[tid];
        sc[tid] = inv;
        sh[tid] = be[tid] - mu * inv;
    }
    for (int i = tid; i < FIN * FOUT; i += blockDim.x) ws[i] = W[i];
    __syncthreads();
    int i = blockIdx.x * blockDim.x + tid;
    if (i >= n) return;
    float di = dinv[i];
    float xr[FIN];
    const float4* ap = (const float4*)(acc + (size_t)i * FIN);
    #pragma unroll
    for (int q = 0; q < FIN / 4; ++q) {
        float4 a = ap[q];
        xr[4*q+0] = fmaxf(fmaf(a.x * di, sc[4*q+0], sh[4*q+0]), 0.f);
        xr[4*q+1] = fmaxf(fmaf(a.y * di, sc[4*q+1], sh[4*q+1]), 0.f);
        xr[4*q+2] = fmaxf(fmaf(a.z * di, sc[4*q+2], sh[4*q+2]), 0.f);
        xr[4*q+3] = fmaxf(fmaf(a.w * di, sc[4*q+3], sh[4*q+3]), 0.f);
    }
    float out[FOUT];
    #pragma unroll
    for (int j = 0; j < FOUT; ++j) {
        float s = 0.f;
        #pragma unroll
        for (int k = 0; k < FIN; ++k) s = fmaf(xr[k], ws[k * FOUT + j], s);
        out[j] = s * di;
    }
    float4* hp = (float4*)(hs + (size_t)i * FOUT);
    #pragma unroll
    for (int q = 0; q < FOUT / 4; ++q) {
        float4 v; v.x = out[4*q+0]; v.y = out[4*q+1]; v.z = out[4*q+2]; v.w = out[4*q+3];
        hp[q] = v;
    }
}

// ---------------- final layer: BN + ReLU + global max (no store) ----------------
__global__ void k_bnmax(const float* __restrict__ acc, const float* __restrict__ dinv,
                        const float* __restrict__ S,
                        const float* __restrict__ g, const float* __restrict__ be,
                        float* __restrict__ maxbuf, int n) {
    __shared__ float sc[8], sh[8];
    int tid = threadIdx.x;
    if (tid < 8) {
        float mu = S[tid] / (float)n;
        float var = S[8 + tid] / (float)n - mu * mu;
        float inv = rsqrtf(var + EPS) * g[tid];
        sc[tid] = inv;
        sh[tid] = be[tid] - mu * inv;
    }
    __syncthreads();
    int i = blockIdx.x * blockDim.x + tid;
    float vals[8];
    #pragma unroll
    for (int j = 0; j < 8; ++j) vals[j] = 0.f;
    if (i < n) {
        float di = dinv[i];
        const float4* ap = (const float4*)(acc + (size_t)i * 8);
        #pragma unroll
        for (int q = 0; q < 2; ++q) {
            float4 a = ap[q];
            vals[4*q+0] = fmaxf(fmaf(a.x * di, sc[4*q+0], sh[4*q+0]), 0.f);
            vals[4*q+1] = fmaxf(fmaf(a.y * di, sc[4*q+1], sh[4*q+1]), 0.f);
            vals[4*q+2] = fmaxf(fmaf(a.z * di, sc[4*q+2], sh[4*q+2]), 0.f);
            vals[4*q+3] = fmaxf(fmaf(a.w * di, sc[4*q+3], sh[4*q+3]), 0.f);
        }
    }
    #pragma unroll
    for (int j = 0; j < 8; ++j) {
        for (int off = 32; off > 0; off >>= 1)
            vals[j] = fmaxf(vals[j], __shfl_down(vals[j], off));
    }
    if ((tid & 63) == 0) {
        #pragma unroll
        for (int j = 0; j < 8; ++j)
            atomicMax((unsigned int*)&maxbuf[j], __float_as_uint(vals[j]));  // vals >= 0
    }
}

// ---------------- final: out = max_pooled . Wout + bout ----------------
__global__ void k_final(const float* __restrict__ maxbuf, const float* __restrict__ Wout,
                        const float* __restrict__ bout, float* __restrict__ out) {
    if (threadIdx.x == 0) {
        float s = bout[0];
        #pragma unroll
        for (int j = 0; j < 8; ++j) s = fmaf(maxbuf[j], Wout[j], s);
        out[0] = s;
    }
}

extern "C" void kernel_launch(void* const* d_in, const int* in_sizes, int n_in,
                              void* d_out, int out_size, void* d_ws, size_t ws_size,
                              hipStream_t stream) {
    const float* x    = (const float*)d_in[0];
    const int*   ei   = (const int*)d_in[1];
    const float* W1   = (const float*)d_in[2];
    const float* g1   = (const float*)d_in[4];
    const float* be1  = (const float*)d_in[5];
    const float* W2   = (const float*)d_in[6];
    const float* g2   = (const float*)d_in[8];
    const float* be2  = (const float*)d_in[9];
    const float* W3   = (const float*)d_in[10];
    const float* g3   = (const float*)d_in[12];
    const float* be3  = (const float*)d_in[13];
    const float* W4   = (const float*)d_in[14];
    const float* g4   = (const float*)d_in[16];
    const float* be4  = (const float*)d_in[17];
    const float* Wout = (const float*)d_in[18];
    const float* bout = (const float*)d_in[19];
    float* out = (float*)d_out;

    const int N = in_sizes[0] / 128;
    const int E = in_sizes[1] / 2;
    const int* src = ei;
    const int* dst = ei + E;

    // workspace layout
    char* ws = (char*)d_ws;
    size_t o = 0;
    int*   deg       = (int*)(ws + o); o += 4 * (size_t)N;
    float* dinv      = (float*)(ws + o); o += 4 * (size_t)N;
    int*   rloc      = (int*)(ws + o); o += 4 * (size_t)N;
    int*   row_start = (int*)(ws + o); o += 4 * ((size_t)N + 16);
    int*   cursor    = (int*)(ws + o); o += 4 * (size_t)N;
    float* stats     = (float*)(ws + o); o += 4096;
    int*   bsum      = (int*)(ws + o); o += 4096;
    float* hs        = (float*)(ws + o); o += 64 * (size_t)N;
    float* acc       = (float*)(ws + o); o += 64 * (size_t)N;
    int*   csr_src   = (int*)(ws + o); o += 4 * (size_t)E;
    float* maxbuf = stats + 128;

    const int B = 256;
    int gN  = (N + B - 1) / B;          // 391
    int gE  = (E + B - 1) / B;
    int gN2 = (2 * N + B - 1) / B;
    int gN4 = (4 * N + B - 1) / B;
    int NB  = gN;

    // ---- one-time graph prep: degrees, dinv, CSR by dst ----
    k_init<<<gN + 1, B, 0, stream>>>(deg, stats, N);
    k_count<<<gE, B, 0, stream>>>(dst, deg, E);
    k_dinv<<<gN, B, 0, stream>>>(deg, dinv, N);
    k_scan_a<<<NB, B, 0, stream>>>(deg, rloc, bsum, N);
    k_scan_b<<<1, 512, 0, stream>>>(bsum, NB);
    k_scan_c<<<NB, B, 0, stream>>>(rloc, bsum, row_start, cursor, N, E);
    k_fill<<<gE, B, 0, stream>>>(dst, src, cursor, csr_src, E);

    // ---- layer 1: 128 -> 8 ----
    k_lin1<<<(N + TN - 1) / TN, B, 0, stream>>>(x, W1, dinv, hs, N);
    k_gather<8><<<gN2, B, 0, stream>>>(row_start, csr_src, hs, dinv, acc, stats + 0, N);

    // ---- layer 2: 8 -> 16 ----
    k_bnlin<8, 16><<<gN, B, 0, stream>>>(acc, dinv, stats + 0, g1, be1, W2, hs, N);
    k_gather<16><<<gN4, B, 0, stream>>>(row_start, csr_src, hs, dinv, acc, stats + 32, N);

    // ---- layer 3: 16 -> 16 ----
    k_bnlin<16, 16><<<gN, B, 0, stream>>>(acc, dinv, stats + 32, g2, be2, W3, hs, N);
    k_gather<16><<<gN4, B, 0, stream>>>(row_start, csr_src, hs, dinv, acc, stats + 64, N);

    // ---- layer 4: 16 -> 8 ----
    k_bnlin<16, 8><<<gN, B, 0, stream>>>(acc, dinv, stats + 64, g3, be3, W4, hs, N);
    k_gather<8><<<gN2, B, 0, stream>>>(row_start, csr_src, hs, dinv, acc, stats + 96, N);

    // ---- BN + ReLU + max-pool + output ----
    k_bnmax<<<gN, B, 0, stream>>>(acc, dinv, stats + 96, g4, be4, maxbuf, N);
    k_final<<<1, 64, 0, stream>>>(maxbuf, Wout, bout, out);
}

// Round 3
// 625.914 us; speedup vs baseline: 6.1369x; 1.4942x over previous
//
#include <hip/hip_runtime.h>
#include <cstddef>

#define EPS 1e-5f
#define TILE 4096   // edges per partition block (16 per thread, block=256)

// ---------------- init: zero stats + bucket histogram ----------------
__global__ void k_init(float* __restrict__ stats, int* __restrict__ bhist) {
    int t = threadIdx.x;            // single block of 512
    if (t < 256) stats[t] = 0.f;    // 4 layers x (S1+S2) + maxbuf at [128..135]
    bhist[t] = 0;                   // 512 >= nbk
}

// ---------------- coarse bucket histogram (dst >> 8), LDS-aggregated ----------------
__global__ void k_bhist(const int* __restrict__ dst, int* __restrict__ bhist,
                        int E, int nbk) {
    __shared__ int hist[512];
    int tid = threadIdx.x;
    int tile0 = blockIdx.x * TILE;
    for (int i = tid; i < nbk; i += 256) hist[i] = 0;
    __syncthreads();
    #pragma unroll
    for (int k = 0; k < 16; ++k) {
        int e = tile0 + k * 256 + tid;
        if (e < E) atomicAdd(&hist[dst[e] >> 8], 1);
    }
    __syncthreads();
    for (int i = tid; i < nbk; i += 256) {
        int c = hist[i];
        if (c) atomicAdd(&bhist[i], c);
    }
}

// ---------------- scan bucket counts -> bucket offsets (1 block of 512) ----------------
__global__ void k_bscan(const int* __restrict__ bhist, int* __restrict__ bcur,
                        int* __restrict__ bstart, int nbk, int E) {
    __shared__ int tmp[512];
    int t = threadIdx.x;
    int v = (t < nbk) ? bhist[t] : 0;
    tmp[t] = v;
    __syncthreads();
    for (int off = 1; off < 512; off <<= 1) {
        int y = (t >= off) ? tmp[t - off] : 0;
        __syncthreads();
        tmp[t] += y;
        __syncthreads();
    }
    if (t < nbk) { int ex = tmp[t] - v; bcur[t] = ex; bstart[t] = ex; }
    if (t == 0) bstart[nbk] = E;
}

// ---------------- partition: edges -> buckets, packed (dlocal<<24)|src ----------------
// src < 2^24 required (N = 100000 ok). Dense cursor frontiers => full-line writes.
__global__ void k_part(const int* __restrict__ src, const int* __restrict__ dst,
                       int* __restrict__ bcur, unsigned int* __restrict__ part,
                       int E, int nbk) {
    __shared__ int hist[512];
    __shared__ int base[512];
    int tid = threadIdx.x;
    int tile0 = blockIdx.x * TILE;
    for (int i = tid; i < nbk; i += 256) hist[i] = 0;
    __syncthreads();
    unsigned int rec[16];
    int bk[16];
    #pragma unroll
    for (int k = 0; k < 16; ++k) {
        int e = tile0 + k * 256 + tid;
        bk[k] = -1;
        if (e < E) {
            int d = dst[e], s = src[e];
            bk[k] = d >> 8;
            rec[k] = ((unsigned int)(d & 255) << 24) | (unsigned int)s;
            atomicAdd(&hist[bk[k]], 1);
        }
    }
    __syncthreads();
    for (int i = tid; i < nbk; i += 256) {
        int c = hist[i];
        base[i] = c ? atomicAdd(&bcur[i], c) : 0;
        hist[i] = 0;
    }
    __syncthreads();
    #pragma unroll
    for (int k = 0; k < 16; ++k) {
        if (bk[k] >= 0) {
            int r = atomicAdd(&hist[bk[k]], 1);
            part[base[bk[k]] + r] = rec[k];
        }
    }
}

// ---------------- per-bucket: node degrees -> row_start + dinv, then csr fill ----------
// One block per bucket of 256 nodes; all scattered writes confined to ~32KB (L2-resident).
__global__ void k_fill2(const unsigned int* __restrict__ part, const int* __restrict__ bstart,
                        float* __restrict__ dinv, int* __restrict__ row_start,
                        int* __restrict__ csr_src, int N) {
    __shared__ int hist[256];
    __shared__ int cur[256];
    __shared__ int wsum[4];
    int b = blockIdx.x, tid = threadIdx.x;
    int nbase = b << 8;
    int span0 = bstart[b], span1 = bstart[b + 1];
    hist[tid] = 0;
    __syncthreads();
    for (int i = span0 + tid; i < span1; i += 256)
        atomicAdd(&hist[part[i] >> 24], 1);
    __syncthreads();
    int v = hist[tid];
    // block-wide exclusive scan over 256
    int lane = tid & 63, wid = tid >> 6;
    int x = v;
    #pragma unroll
    for (int off = 1; off < 64; off <<= 1) {
        int y = __shfl_up(x, off);
        if (lane >= off) x += y;
    }
    if (lane == 63) wsum[wid] = x;
    __syncthreads();
    int add = 0;
    for (int w = 0; w < wid; ++w) add += wsum[w];
    int incl = x + add;
    int rs = span0 + incl - v;          // global exclusive offset
    int node = nbase + tid;
    if (node < N) {
        row_start[node] = rs;
        dinv[node] = rsqrtf((float)(v + 1));   // +1 self loop
        if (node == N - 1) row_start[N] = rs + v;
    }
    cur[tid] = rs;
    __syncthreads();
    for (int i = span0 + tid; i < span1; i += 256) {
        unsigned int rec = part[i];
        int p = atomicAdd(&cur[rec >> 24], 1);
        csr_src[p] = (int)(rec & 0xFFFFFFu);
    }
}

// ---------------- layer 1 linear: 128 -> 8, LDS-tiled ----------------
#define TN 64
__global__ void k_lin1(const float* __restrict__ x, const float* __restrict__ W,
                       const float* __restrict__ dinv,
                       float* __restrict__ hs, int n) {
    __shared__ float xs[TN * 132];
    __shared__ float ws[128 * 8];
    int tid = threadIdx.x;
    int base = blockIdx.x * TN;
    for (int i = tid; i < 1024; i += 256) ws[i] = W[i];
    int nvalid = n - base; if (nvalid > TN) nvalid = TN;
    int limit4 = nvalid * 32;
    const float4* x4 = (const float4*)(x + (size_t)base * 128);
    float4* xs4 = (float4*)xs;
    for (int i = tid; i < TN * 32; i += 256) {
        if (i < limit4) {
            int row = i >> 5, col = i & 31;
            xs4[row * 33 + col] = x4[i];
        }
    }
    __syncthreads();
    #pragma unroll
    for (int rep = 0; rep < 2; ++rep) {
        int o = rep * 256 + tid;
        int node = o >> 3, feat = o & 7;
        if (node < nvalid) {
            const float* xr = xs + node * 132;
            float s = 0.f;
            #pragma unroll 8
            for (int k = 0; k < 128; ++k) s = fmaf(xr[k], ws[k * 8 + feat], s);
            s *= dinv[base + node];
            hs[(size_t)(base + node) * 8 + feat] = s;
        }
    }
}

// ---------------- CSR gather + fused BN-stats ----------------
template<int F>
__global__ void k_gather(const int* __restrict__ row_start, const int* __restrict__ csr_src,
                         const float* __restrict__ hs, const float* __restrict__ dinv,
                         float* __restrict__ acc, float* __restrict__ S, int n) {
    constexpr int P = F / 4;
    constexpr int SHIFT = (P == 2) ? 1 : 2;
    __shared__ float ls[2 * F];
    if (threadIdx.x < 2 * F) ls[threadIdx.x] = 0.f;
    __syncthreads();

    int t = blockIdx.x * blockDim.x + threadIdx.x;
    int node = t >> SHIFT;
    int part = t & (P - 1);
    int lane = threadIdx.x & 63;

    float4 a = make_float4(0.f, 0.f, 0.f, 0.f);
    float di = 0.f;
    if (node < n) {
        const float4* hp = (const float4*)hs;
        a = hp[(size_t)node * P + part];      // self-loop term
        int e = row_start[node], end = row_start[node + 1];
        int s_next = (e < end) ? csr_src[e] : 0;
        while (e < end) {
            int s = s_next;
            ++e;
            if (e < end) s_next = csr_src[e];
            float4 v = hp[(size_t)s * P + part];
            a.x += v.x; a.y += v.y; a.z += v.z; a.w += v.w;
        }
        ((float4*)acc)[(size_t)node * P + part] = a;
        di = dinv[node];
    }
    float vx = a.x * di, vy = a.y * di, vz = a.z * di, vw = a.w * di;
    float s1x = vx, s1y = vy, s1z = vz, s1w = vw;
    float s2x = vx * vx, s2y = vy * vy, s2z = vz * vz, s2w = vw * vw;
    #pragma unroll
    for (int off = P; off < 64; off <<= 1) {
        s1x += __shfl_down(s1x, off); s1y += __shfl_down(s1y, off);
        s1z += __shfl_down(s1z, off); s1w += __shfl_down(s1w, off);
        s2x += __shfl_down(s2x, off); s2y += __shfl_down(s2y, off);
        s2z += __shfl_down(s2z, off); s2w += __shfl_down(s2w, off);
    }
    if (lane < P) {
        int j = part * 4;
        atomicAdd(&ls[j + 0], s1x); atomicAdd(&ls[j + 1], s1y);
        atomicAdd(&ls[j + 2], s1z); atomicAdd(&ls[j + 3], s1w);
        atomicAdd(&ls[F + j + 0], s2x); atomicAdd(&ls[F + j + 1], s2y);
        atomicAdd(&ls[F + j + 2], s2z); atomicAdd(&ls[F + j + 3], s2w);
    }
    __syncthreads();
    if (threadIdx.x < 2 * F) atomicAdd(&S[threadIdx.x], ls[threadIdx.x]);
}

// ---------------- fused BN + ReLU + next linear ----------------
template<int FIN, int FOUT>
__global__ void k_bnlin(const float* __restrict__ acc, const float* __restrict__ dinv,
                        const float* __restrict__ S,
                        const float* __restrict__ g, const float* __restrict__ be,
                        const float* __restrict__ W,
                        float* __restrict__ hs, int n) {
    __shared__ float sc[FIN], sh[FIN], ws[FIN * FOUT];
    int tid = threadIdx.x;
    if (tid < FIN) {
        float mu = S[tid] / (float)n;
        float var = S[FIN + tid] / (float)n - mu * mu;
        float inv = rsqrtf(var + EPS) * g[tid];
        sc[tid] = inv;
        sh[tid] = be[tid] - mu * inv;
    }
    for (int i = tid; i < FIN * FOUT; i += blockDim.x) ws[i] = W[i];
    __syncthreads();
    int i = blockIdx.x * blockDim.x + tid;
    if (i >= n) return;
    float di = dinv[i];
    float xr[FIN];
    const float4* ap = (const float4*)(acc + (size_t)i * FIN);
    #pragma unroll
    for (int q = 0; q < FIN / 4; ++q) {
        float4 a = ap[q];
        xr[4*q+0] = fmaxf(fmaf(a.x * di, sc[4*q+0], sh[4*q+0]), 0.f);
        xr[4*q+1] = fmaxf(fmaf(a.y * di, sc[4*q+1], sh[4*q+1]), 0.f);
        xr[4*q+2] = fmaxf(fmaf(a.z * di, sc[4*q+2], sh[4*q+2]), 0.f);
        xr[4*q+3] = fmaxf(fmaf(a.w * di, sc[4*q+3], sh[4*q+3]), 0.f);
    }
    float out[FOUT];
    #pragma unroll
    for (int j = 0; j < FOUT; ++j) {
        float s = 0.f;
        #pragma unroll
        for (int k = 0; k < FIN; ++k) s = fmaf(xr[k], ws[k * FOUT + j], s);
        out[j] = s * di;
    }
    float4* hp = (float4*)(hs + (size_t)i * FOUT);
    #pragma unroll
    for (int q = 0; q < FOUT / 4; ++q) {
        float4 v; v.x = out[4*q+0]; v.y = out[4*q+1]; v.z = out[4*q+2]; v.w = out[4*q+3];
        hp[q] = v;
    }
}

// ---------------- final layer: BN + ReLU + global max ----------------
__global__ void k_bnmax(const float* __restrict__ acc, const float* __restrict__ dinv,
                        const float* __restrict__ S,
                        const float* __restrict__ g, const float* __restrict__ be,
                        float* __restrict__ maxbuf, int n) {
    __shared__ float sc[8], sh[8];
    int tid = threadIdx.x;
    if (tid < 8) {
        float mu = S[tid] / (float)n;
        float var = S[8 + tid] / (float)n - mu * mu;
        float inv = rsqrtf(var + EPS) * g[tid];
        sc[tid] = inv;
        sh[tid] = be[tid] - mu * inv;
    }
    __syncthreads();
    int i = blockIdx.x * blockDim.x + tid;
    float vals[8];
    #pragma unroll
    for (int j = 0; j < 8; ++j) vals[j] = 0.f;
    if (i < n) {
        float di = dinv[i];
        const float4* ap = (const float4*)(acc + (size_t)i * 8);
        #pragma unroll
        for (int q = 0; q < 2; ++q) {
            float4 a = ap[q];
            vals[4*q+0] = fmaxf(fmaf(a.x * di, sc[4*q+0], sh[4*q+0]), 0.f);
            vals[4*q+1] = fmaxf(fmaf(a.y * di, sc[4*q+1], sh[4*q+1]), 0.f);
            vals[4*q+2] = fmaxf(fmaf(a.z * di, sc[4*q+2], sh[4*q+2]), 0.f);
            vals[4*q+3] = fmaxf(fmaf(a.w * di, sc[4*q+3], sh[4*q+3]), 0.f);
        }
    }
    #pragma unroll
    for (int j = 0; j < 8; ++j) {
        for (int off = 32; off > 0; off >>= 1)
            vals[j] = fmaxf(vals[j], __shfl_down(vals[j], off));
    }
    if ((tid & 63) == 0) {
        #pragma unroll
        for (int j = 0; j < 8; ++j)
            atomicMax((unsigned int*)&maxbuf[j], __float_as_uint(vals[j]));
    }
}

__global__ void k_final(const float* __restrict__ maxbuf, const float* __restrict__ Wout,
                        const float* __restrict__ bout, float* __restrict__ out) {
    if (threadIdx.x == 0) {
        float s = bout[0];
        #pragma unroll
        for (int j = 0; j < 8; ++j) s = fmaf(maxbuf[j], Wout[j], s);
        out[0] = s;
    }
}

extern "C" void kernel_launch(void* const* d_in, const int* in_sizes, int n_in,
                              void* d_out, int out_size, void* d_ws, size_t ws_size,
                              hipStream_t stream) {
    const float* x    = (const float*)d_in[0];
    const int*   ei   = (const int*)d_in[1];
    const float* W1   = (const float*)d_in[2];
    const float* g1   = (const float*)d_in[4];
    const float* be1  = (const float*)d_in[5];
    const float* W2   = (const float*)d_in[6];
    const float* g2   = (const float*)d_in[8];
    const float* be2  = (const float*)d_in[9];
    const float* W3   = (const float*)d_in[10];
    const float* g3   = (const float*)d_in[12];
    const float* be3  = (const float*)d_in[13];
    const float* W4   = (const float*)d_in[14];
    const float* g4   = (const float*)d_in[16];
    const float* be4  = (const float*)d_in[17];
    const float* Wout = (const float*)d_in[18];
    const float* bout = (const float*)d_in[19];
    float* out = (float*)d_out;

    const int N = in_sizes[0] / 128;
    const int E = in_sizes[1] / 2;
    const int* src = ei;
    const int* dst = ei + E;
    const int nbk = (N + 255) >> 8;          // 256-node buckets

    // workspace layout
    char* ws = (char*)d_ws;
    size_t o = 0;
    float* dinv      = (float*)(ws + o); o += 4 * (size_t)N;
    int*   row_start = (int*)(ws + o);   o += 4 * ((size_t)N + 16);
    float* stats     = (float*)(ws + o); o += 4096;
    int*   bhist     = (int*)(ws + o);   o += 2048;
    int*   bcur      = (int*)(ws + o);   o += 2048;
    int*   bstart    = (int*)(ws + o);   o += 4096;
    size_t hsacc = 128 * (size_t)N;
    if ((size_t)4 * E > hsacc) hsacc = (size_t)4 * E;
    float* hs        = (float*)(ws + o);
    float* acc       = (float*)(ws + o + 64 * (size_t)N);
    unsigned int* part = (unsigned int*)(ws + o);   // aliases hs+acc (dead before k_lin1)
    o += hsacc;
    int*   csr_src   = (int*)(ws + o);   o += 4 * (size_t)E;
    float* maxbuf = stats + 128;

    const int B = 256;
    int gN  = (N + B - 1) / B;
    int gN2 = (2 * N + B - 1) / B;
    int gN4 = (4 * N + B - 1) / B;
    int gT  = (E + TILE - 1) / TILE;

    // ---- graph prep: bucket hist -> scan -> partition -> per-bucket fill ----
    k_init<<<1, 512, 0, stream>>>(stats, bhist);
    k_bhist<<<gT, B, 0, stream>>>(dst, bhist, E, nbk);
    k_bscan<<<1, 512, 0, stream>>>(bhist, bcur, bstart, nbk, E);
    k_part<<<gT, B, 0, stream>>>(src, dst, bcur, part, E, nbk);
    k_fill2<<<nbk, B, 0, stream>>>(part, bstart, dinv, row_start, csr_src, N);

    // ---- layer 1: 128 -> 8 ----
    k_lin1<<<(N + TN - 1) / TN, B, 0, stream>>>(x, W1, dinv, hs, N);
    k_gather<8><<<gN2, B, 0, stream>>>(row_start, csr_src, hs, dinv, acc, stats + 0, N);

    // ---- layer 2: 8 -> 16 ----
    k_bnlin<8, 16><<<gN, B, 0, stream>>>(acc, dinv, stats + 0, g1, be1, W2, hs, N);
    k_gather<16><<<gN4, B, 0, stream>>>(row_start, csr_src, hs, dinv, acc, stats + 32, N);

    // ---- layer 3: 16 -> 16 ----
    k_bnlin<16, 16><<<gN, B, 0, stream>>>(acc, dinv, stats + 32, g2, be2, W3, hs, N);
    k_gather<16><<<gN4, B, 0, stream>>>(row_start, csr_src, hs, dinv, acc, stats + 64, N);

    // ---- layer 4: 16 -> 8 ----
    k_bnlin<16, 8><<<gN, B, 0, stream>>>(acc, dinv, stats + 64, g3, be3, W4, hs, N);
    k_gather<8><<<gN2, B, 0, stream>>>(row_start, csr_src, hs, dinv, acc, stats + 96, N);

    // ---- BN + ReLU + max-pool + output ----
    k_bnmax<<<gN, B, 0, stream>>>(acc, dinv, stats + 96, g4, be4, maxbuf, N);
    k_final<<<1, 64, 0, stream>>>(maxbuf, Wout, bout, out);
}

// Round 4
// 600.100 us; speedup vs baseline: 6.4009x; 1.0430x over previous
//
#include <hip/hip_runtime.h>
#include <cstddef>

#define EPS 1e-5f
#define TILE 32768   // edges per partition block (128 rounds of 256)

// ---------------- init: zero stats ----------------
__global__ void k_init(float* __restrict__ stats) {
    stats[threadIdx.x] = 0.f;    // 4 layers x (S1+S2) blocks of 32 floats
}

// ---------------- per-block bucket histogram -> cells[bucket][block] ------------
__global__ void k_hist2d(const int* __restrict__ dst, int* __restrict__ cells,
                         int E, int nbk, int gT) {
    __shared__ int hist[512];
    int tid = threadIdx.x;
    for (int i = tid; i < nbk; i += 256) hist[i] = 0;
    __syncthreads();
    int tile0 = blockIdx.x * TILE;
    #pragma unroll 4
    for (int r = 0; r < TILE / 256; ++r) {
        int e = tile0 + r * 256 + tid;
        if (e < E) atomicAdd(&hist[dst[e] >> 8], 1);
    }
    __syncthreads();
    for (int i = tid; i < nbk; i += 256) cells[i * gT + blockIdx.x] = hist[i];
}

// ---------------- exclusive scan over all cells (1 block of 1024) ----------------
__global__ void k_scan1b(int* __restrict__ cells, int T) {
    __shared__ int tmp[1024];
    int t = threadIdx.x;
    int per = (T + 1023) >> 10;
    int lo = t * per, hi = lo + per;
    if (hi > T) hi = T;
    int s = 0;
    for (int i = lo; i < hi; ++i) s += cells[i];
    tmp[t] = s;
    __syncthreads();
    for (int off = 1; off < 1024; off <<= 1) {
        int y = (t >= off) ? tmp[t - off] : 0;
        __syncthreads();
        tmp[t] += y;
        __syncthreads();
    }
    int run = tmp[t] - s;
    for (int i = lo; i < hi; ++i) { int c = cells[i]; cells[i] = run; run += c; }
}

// ---------------- partition: scatter to private (bucket,block) ranges ------------
// packed rec = (dlocal<<24)|src ; src < 2^24 (N = 100000 ok). Zero global atomics.
__global__ void k_part2(const int* __restrict__ src, const int* __restrict__ dst,
                        const int* __restrict__ cells, unsigned int* __restrict__ part,
                        int E, int nbk, int gT) {
    __shared__ int cur[512];
    int tid = threadIdx.x;
    for (int i = tid; i < nbk; i += 256) cur[i] = cells[i * gT + blockIdx.x];
    __syncthreads();
    int tile0 = blockIdx.x * TILE;
    #pragma unroll 4
    for (int r = 0; r < TILE / 256; ++r) {
        int e = tile0 + r * 256 + tid;
        if (e < E) {
            int d = dst[e], s = src[e];
            int p = atomicAdd(&cur[d >> 8], 1);
            part[p] = ((unsigned int)(d & 255) << 24) | (unsigned int)s;
        }
    }
}

// ---------------- per-bucket: degrees -> row_start + dinv, then csr fill ----------
__global__ void k_fill2(const unsigned int* __restrict__ part, const int* __restrict__ cells,
                        float* __restrict__ dinv, int* __restrict__ row_start,
                        int* __restrict__ csr_src, int N, int E, int nbk, int gT) {
    __shared__ int hist[256];
    __shared__ int cur[256];
    __shared__ int wsum[4];
    int b = blockIdx.x, tid = threadIdx.x;
    int nbase = b << 8;
    int span0 = cells[b * gT];
    int span1 = (b == nbk - 1) ? E : cells[(b + 1) * gT];
    hist[tid] = 0;
    __syncthreads();
    for (int i = span0 + tid; i < span1; i += 256)
        atomicAdd(&hist[part[i] >> 24], 1);
    __syncthreads();
    int v = hist[tid];
    int lane = tid & 63, wid = tid >> 6;
    int x = v;
    #pragma unroll
    for (int off = 1; off < 64; off <<= 1) {
        int y = __shfl_up(x, off);
        if (lane >= off) x += y;
    }
    if (lane == 63) wsum[wid] = x;
    __syncthreads();
    int add = 0;
    for (int w = 0; w < wid; ++w) add += wsum[w];
    int incl = x + add;
    int rs = span0 + incl - v;          // global exclusive offset
    int node = nbase + tid;
    if (node < N) {
        row_start[node] = rs;
        dinv[node] = rsqrtf((float)(v + 1));   // +1 self loop
        if (node == N - 1) row_start[N] = rs + v;
    }
    cur[tid] = rs;
    __syncthreads();
    for (int i = span0 + tid; i < span1; i += 256) {
        unsigned int rec = part[i];
        int p = atomicAdd(&cur[rec >> 24], 1);
        csr_src[p] = (int)(rec & 0xFFFFFFu);
    }
}

// ---------------- layer 1 linear: 128 -> 8, LDS-tiled ----------------
#define TN 64
__global__ void k_lin1(const float* __restrict__ x, const float* __restrict__ W,
                       const float* __restrict__ dinv,
                       float* __restrict__ hs, int n) {
    __shared__ float xs[TN * 132];
    __shared__ float ws[128 * 8];
    int tid = threadIdx.x;
    int base = blockIdx.x * TN;
    for (int i = tid; i < 1024; i += 256) ws[i] = W[i];
    int nvalid = n - base; if (nvalid > TN) nvalid = TN;
    int limit4 = nvalid * 32;
    const float4* x4 = (const float4*)(x + (size_t)base * 128);
    float4* xs4 = (float4*)xs;
    for (int i = tid; i < TN * 32; i += 256) {
        if (i < limit4) {
            int row = i >> 5, col = i & 31;
            xs4[row * 33 + col] = x4[i];
        }
    }
    __syncthreads();
    #pragma unroll
    for (int rep = 0; rep < 2; ++rep) {
        int o = rep * 256 + tid;
        int node = o >> 3, feat = o & 7;
        if (node < nvalid) {
            const float* xr = xs + node * 132;
            float s = 0.f;
            #pragma unroll 8
            for (int k = 0; k < 128; ++k) s = fmaf(xr[k], ws[k * 8 + feat], s);
            s *= dinv[base + node];
            hs[(size_t)(base + node) * 8 + feat] = s;
        }
    }
}

// ---------------- CSR gather + fused BN-stats ----------------
template<int F>
__global__ void k_gather(const int* __restrict__ row_start, const int* __restrict__ csr_src,
                         const float* __restrict__ hs, const float* __restrict__ dinv,
                         float* __restrict__ acc, float* __restrict__ S, int n) {
    constexpr int P = F / 4;
    constexpr int SHIFT = (P == 2) ? 1 : 2;
    __shared__ float ls[2 * F];
    if (threadIdx.x < 2 * F) ls[threadIdx.x] = 0.f;
    __syncthreads();

    int t = blockIdx.x * blockDim.x + threadIdx.x;
    int node = t >> SHIFT;
    int part = t & (P - 1);
    int lane = threadIdx.x & 63;

    float4 a = make_float4(0.f, 0.f, 0.f, 0.f);
    float di = 0.f;
    if (node < n) {
        const float4* hp = (const float4*)hs;
        a = hp[(size_t)node * P + part];      // self-loop term
        int e = row_start[node], end = row_start[node + 1];
        int s_next = (e < end) ? csr_src[e] : 0;
        while (e < end) {
            int s = s_next;
            ++e;
            if (e < end) s_next = csr_src[e];
            float4 v = hp[(size_t)s * P + part];
            a.x += v.x; a.y += v.y; a.z += v.z; a.w += v.w;
        }
        ((float4*)acc)[(size_t)node * P + part] = a;
        di = dinv[node];
    }
    float vx = a.x * di, vy = a.y * di, vz = a.z * di, vw = a.w * di;
    float s1x = vx, s1y = vy, s1z = vz, s1w = vw;
    float s2x = vx * vx, s2y = vy * vy, s2z = vz * vz, s2w = vw * vw;
    #pragma unroll
    for (int off = P; off < 64; off <<= 1) {
        s1x += __shfl_down(s1x, off); s1y += __shfl_down(s1y, off);
        s1z += __shfl_down(s1z, off); s1w += __shfl_down(s1w, off);
        s2x += __shfl_down(s2x, off); s2y += __shfl_down(s2y, off);
        s2z += __shfl_down(s2z, off); s2w += __shfl_down(s2w, off);
    }
    if (lane < P) {
        int j = part * 4;
        atomicAdd(&ls[j + 0], s1x); atomicAdd(&ls[j + 1], s1y);
        atomicAdd(&ls[j + 2], s1z); atomicAdd(&ls[j + 3], s1w);
        atomicAdd(&ls[F + j + 0], s2x); atomicAdd(&ls[F + j + 1], s2y);
        atomicAdd(&ls[F + j + 2], s2z); atomicAdd(&ls[F + j + 3], s2w);
    }
    __syncthreads();
    if (threadIdx.x < 2 * F) atomicAdd(&S[threadIdx.x], ls[threadIdx.x]);
}

// ---------------- fused BN + ReLU + next linear ----------------
template<int FIN, int FOUT>
__global__ void k_bnlin(const float* __restrict__ acc, const float* __restrict__ dinv,
                        const float* __restrict__ S,
                        const float* __restrict__ g, const float* __restrict__ be,
                        const float* __restrict__ W,
                        float* __restrict__ hs, int n) {
    __shared__ float sc[FIN], sh[FIN], ws[FIN * FOUT];
    int tid = threadIdx.x;
    if (tid < FIN) {
        float mu = S[tid] / (float)n;
        float var = S[FIN + tid] / (float)n - mu * mu;
        float inv = rsqrtf(var + EPS) * g[tid];
        sc[tid] = inv;
        sh[tid] = be[tid] - mu * inv;
    }
    for (int i = tid; i < FIN * FOUT; i += blockDim.x) ws[i] = W[i];
    __syncthreads();
    int i = blockIdx.x * blockDim.x + tid;
    if (i >= n) return;
    float di = dinv[i];
    float xr[FIN];
    const float4* ap = (const float4*)(acc + (size_t)i * FIN);
    #pragma unroll
    for (int q = 0; q < FIN / 4; ++q) {
        float4 a = ap[q];
        xr[4*q+0] = fmaxf(fmaf(a.x * di, sc[4*q+0], sh[4*q+0]), 0.f);
        xr[4*q+1] = fmaxf(fmaf(a.y * di, sc[4*q+1], sh[4*q+1]), 0.f);
        xr[4*q+2] = fmaxf(fmaf(a.z * di, sc[4*q+2], sh[4*q+2]), 0.f);
        xr[4*q+3] = fmaxf(fmaf(a.w * di, sc[4*q+3], sh[4*q+3]), 0.f);
    }
    float out[FOUT];
    #pragma unroll
    for (int j = 0; j < FOUT; ++j) {
        float s = 0.f;
        #pragma unroll
        for (int k = 0; k < FIN; ++k) s = fmaf(xr[k], ws[k * FOUT + j], s);
        out[j] = s * di;
    }
    float4* hp = (float4*)(hs + (size_t)i * FOUT);
    #pragma unroll
    for (int q = 0; q < FOUT / 4; ++q) {
        float4 v; v.x = out[4*q+0]; v.y = out[4*q+1]; v.z = out[4*q+2]; v.w = out[4*q+3];
        hp[q] = v;
    }
}

// ---------------- final layer: BN + ReLU + per-block max (no atomics) ------------
__global__ void k_bnmax(const float* __restrict__ acc, const float* __restrict__ dinv,
                        const float* __restrict__ S,
                        const float* __restrict__ g, const float* __restrict__ be,
                        float* __restrict__ bmax, int n) {
    __shared__ float sc[8], sh[8];
    __shared__ float wmax[4 * 8];
    int tid = threadIdx.x;
    if (tid < 8) {
        float mu = S[tid] / (float)n;
        float var = S[8 + tid] / (float)n - mu * mu;
        float inv = rsqrtf(var + EPS) * g[tid];
        sc[tid] = inv;
        sh[tid] = be[tid] - mu * inv;
    }
    __syncthreads();
    int i = blockIdx.x * blockDim.x + tid;
    float vals[8];
    #pragma unroll
    for (int j = 0; j < 8; ++j) vals[j] = 0.f;
    if (i < n) {
        float di = dinv[i];
        const float4* ap = (const float4*)(acc + (size_t)i * 8);
        #pragma unroll
        for (int q = 0; q < 2; ++q) {
            float4 a = ap[q];
            vals[4*q+0] = fmaxf(fmaf(a.x * di, sc[4*q+0], sh[4*q+0]), 0.f);
            vals[4*q+1] = fmaxf(fmaf(a.y * di, sc[4*q+1], sh[4*q+1]), 0.f);
            vals[4*q+2] = fmaxf(fmaf(a.z * di, sc[4*q+2], sh[4*q+2]), 0.f);
            vals[4*q+3] = fmaxf(fmaf(a.w * di, sc[4*q+3], sh[4*q+3]), 0.f);
        }
    }
    #pragma unroll
    for (int j = 0; j < 8; ++j) {
        #pragma unroll
        for (int off = 32; off > 0; off >>= 1)
            vals[j] = fmaxf(vals[j], __shfl_down(vals[j], off));
    }
    int lane = tid & 63, wid = tid >> 6;
    if (lane == 0) {
        #pragma unroll
        for (int j = 0; j < 8; ++j) wmax[wid * 8 + j] = vals[j];
    }
    __syncthreads();
    if (tid < 8) {
        float m = wmax[tid];
        #pragma unroll
        for (int w = 1; w < 4; ++w) m = fmaxf(m, wmax[w * 8 + tid]);
        bmax[blockIdx.x * 8 + tid] = m;
    }
}

// ---------------- final: reduce per-block maxima, dot with Wout ----------------
__global__ void k_final(const float* __restrict__ bmax, const float* __restrict__ Wout,
                        const float* __restrict__ bout, float* __restrict__ out, int nb) {
    __shared__ float red[64 * 8];
    int tid = threadIdx.x;            // 512 threads: (chunk c, feature j)
    int j = tid & 7, c = tid >> 3;
    float m = 0.f;
    for (int b = c; b < nb; b += 64) m = fmaxf(m, bmax[b * 8 + j]);
    red[c * 8 + j] = m;
    __syncthreads();
    if (tid < 8) {
        float mm = red[tid];
        for (int cc = 1; cc < 64; ++cc) mm = fmaxf(mm, red[cc * 8 + tid]);
        red[tid] = mm;
    }
    __syncthreads();
    if (tid == 0) {
        float s = bout[0];
        #pragma unroll
        for (int k = 0; k < 8; ++k) s = fmaf(red[k], Wout[k], s);
        out[0] = s;
    }
}

extern "C" void kernel_launch(void* const* d_in, const int* in_sizes, int n_in,
                              void* d_out, int out_size, void* d_ws, size_t ws_size,
                              hipStream_t stream) {
    const float* x    = (const float*)d_in[0];
    const int*   ei   = (const int*)d_in[1];
    const float* W1   = (const float*)d_in[2];
    const float* g1   = (const float*)d_in[4];
    const float* be1  = (const float*)d_in[5];
    const float* W2   = (const float*)d_in[6];
    const float* g2   = (const float*)d_in[8];
    const float* be2  = (const float*)d_in[9];
    const float* W3   = (const float*)d_in[10];
    const float* g3   = (const float*)d_in[12];
    const float* be3  = (const float*)d_in[13];
    const float* W4   = (const float*)d_in[14];
    const float* g4   = (const float*)d_in[16];
    const float* be4  = (const float*)d_in[17];
    const float* Wout = (const float*)d_in[18];
    const float* bout = (const float*)d_in[19];
    float* out = (float*)d_out;

    const int N = in_sizes[0] / 128;
    const int E = in_sizes[1] / 2;
    const int* src = ei;
    const int* dst = ei + E;
    const int nbk = (N + 255) >> 8;              // 256-node buckets (391)
    const int gT  = (E + TILE - 1) / TILE;       // partition blocks (98)

    // workspace layout
    char* ws = (char*)d_ws;
    size_t o = 0;
    float* dinv      = (float*)(ws + o); o += 4 * (size_t)N;
    int*   row_start = (int*)(ws + o);   o += 4 * ((size_t)N + 16);
    float* stats     = (float*)(ws + o); o += 4096;
    int*   cells     = (int*)(ws + o);   o += 4 * (size_t)((nbk + 1) * gT + 64);
    float* bmax      = (float*)(ws + o); o += 4 * (size_t)(((N + 255) / 256) * 8 + 64);
    size_t hsacc = 128 * (size_t)N;
    if ((size_t)4 * E > hsacc) hsacc = (size_t)4 * E;
    float* hs        = (float*)(ws + o);
    float* acc       = (float*)(ws + o + 64 * (size_t)N);
    unsigned int* part = (unsigned int*)(ws + o);   // aliases hs+acc (dead before k_lin1)
    o += hsacc;
    int*   csr_src   = (int*)(ws + o);   o += 4 * (size_t)E;

    const int B = 256;
    int gN  = (N + B - 1) / B;
    int gN2 = (2 * N + B - 1) / B;
    int gN4 = (4 * N + B - 1) / B;

    // ---- graph prep: per-block hist -> scan -> atomic-free partition -> fill ----
    k_init<<<1, 256, 0, stream>>>(stats);
    k_hist2d<<<gT, B, 0, stream>>>(dst, cells, E, nbk, gT);
    k_scan1b<<<1, 1024, 0, stream>>>(cells, nbk * gT);
    k_part2<<<gT, B, 0, stream>>>(src, dst, cells, part, E, nbk, gT);
    k_fill2<<<nbk, B, 0, stream>>>(part, cells, dinv, row_start, csr_src, N, E, nbk, gT);

    // ---- layer 1: 128 -> 8 ----
    k_lin1<<<(N + TN - 1) / TN, B, 0, stream>>>(x, W1, dinv, hs, N);
    k_gather<8><<<gN2, B, 0, stream>>>(row_start, csr_src, hs, dinv, acc, stats + 0, N);

    // ---- layer 2: 8 -> 16 ----
    k_bnlin<8, 16><<<gN, B, 0, stream>>>(acc, dinv, stats + 0, g1, be1, W2, hs, N);
    k_gather<16><<<gN4, B, 0, stream>>>(row_start, csr_src, hs, dinv, acc, stats + 32, N);

    // ---- layer 3: 16 -> 16 ----
    k_bnlin<16, 16><<<gN, B, 0, stream>>>(acc, dinv, stats + 32, g2, be2, W3, hs, N);
    k_gather<16><<<gN4, B, 0, stream>>>(row_start, csr_src, hs, dinv, acc, stats + 64, N);

    // ---- layer 4: 16 -> 8 ----
    k_bnlin<16, 8><<<gN, B, 0, stream>>>(acc, dinv, stats + 64, g3, be3, W4, hs, N);
    k_gather<8><<<gN2, B, 0, stream>>>(row_start, csr_src, hs, dinv, acc, stats + 96, N);

    // ---- BN + ReLU + max-pool + output ----
    k_bnmax<<<gN, B, 0, stream>>>(acc, dinv, stats + 96, g4, be4, bmax, N);
    k_final<<<1, 512, 0, stream>>>(bmax, Wout, bout, out, gN);
}

// Round 5
// 487.096 us; speedup vs baseline: 7.8859x; 1.2320x over previous
//
#include <hip/hip_runtime.h>
#include <hip/hip_fp16.h>
#include <cstddef>

#define EPS 1e-5f
#define TILE 32768   // edges per partition block (128 rounds of 256)

// ---------------- init: zero stats ----------------
__global__ void k_init(float* __restrict__ stats) {
    stats[threadIdx.x] = 0.f;    // 4 layers x (S1+S2) blocks of 32 floats
}

// ---------------- per-block bucket histogram -> cells[bucket][block] ------------
__global__ void k_hist2d(const int* __restrict__ dst, int* __restrict__ cells,
                         int E, int nbk, int gT) {
    __shared__ int hist[512];
    int tid = threadIdx.x;
    for (int i = tid; i < nbk; i += 256) hist[i] = 0;
    __syncthreads();
    int tile0 = blockIdx.x * TILE;
    #pragma unroll 4
    for (int r = 0; r < TILE / 256; ++r) {
        int e = tile0 + r * 256 + tid;
        if (e < E) atomicAdd(&hist[dst[e] >> 8], 1);
    }
    __syncthreads();
    for (int i = tid; i < nbk; i += 256) cells[i * gT + blockIdx.x] = hist[i];
}

// ---------------- exclusive scan over all cells (1 block of 1024) ----------------
__global__ void k_scan1b(int* __restrict__ cells, int T) {
    __shared__ int tmp[1024];
    int t = threadIdx.x;
    int per = (T + 1023) >> 10;
    int lo = t * per, hi = lo + per;
    if (hi > T) hi = T;
    int s = 0;
    for (int i = lo; i < hi; ++i) s += cells[i];
    tmp[t] = s;
    __syncthreads();
    for (int off = 1; off < 1024; off <<= 1) {
        int y = (t >= off) ? tmp[t - off] : 0;
        __syncthreads();
        tmp[t] += y;
        __syncthreads();
    }
    int run = tmp[t] - s;
    for (int i = lo; i < hi; ++i) { int c = cells[i]; cells[i] = run; run += c; }
}

// ---------------- partition: scatter to private (bucket,block) ranges ------------
// packed rec = (dlocal<<24)|src ; src < 2^24 (N = 100000 ok). Zero global atomics.
__global__ void k_part2(const int* __restrict__ src, const int* __restrict__ dst,
                        const int* __restrict__ cells, unsigned int* __restrict__ part,
                        int E, int nbk, int gT) {
    __shared__ int cur[512];
    int tid = threadIdx.x;
    for (int i = tid; i < nbk; i += 256) cur[i] = cells[i * gT + blockIdx.x];
    __syncthreads();
    int tile0 = blockIdx.x * TILE;
    #pragma unroll 4
    for (int r = 0; r < TILE / 256; ++r) {
        int e = tile0 + r * 256 + tid;
        if (e < E) {
            int d = dst[e], s = src[e];
            int p = atomicAdd(&cur[d >> 8], 1);
            part[p] = ((unsigned int)(d & 255) << 24) | (unsigned int)s;
        }
    }
}

// ---------------- per-bucket: degrees -> row_start + dinv, then csr fill ----------
__global__ void k_fill2(const unsigned int* __restrict__ part, const int* __restrict__ cells,
                        float* __restrict__ dinv, int* __restrict__ row_start,
                        int* __restrict__ csr_src, int N, int E, int nbk, int gT) {
    __shared__ int hist[256];
    __shared__ int cur[256];
    __shared__ int wsum[4];
    int b = blockIdx.x, tid = threadIdx.x;
    int nbase = b << 8;
    int span0 = cells[b * gT];
    int span1 = (b == nbk - 1) ? E : cells[(b + 1) * gT];
    hist[tid] = 0;
    __syncthreads();
    for (int i = span0 + tid; i < span1; i += 256)
        atomicAdd(&hist[part[i] >> 24], 1);
    __syncthreads();
    int v = hist[tid];
    int lane = tid & 63, wid = tid >> 6;
    int x = v;
    #pragma unroll
    for (int off = 1; off < 64; off <<= 1) {
        int y = __shfl_up(x, off);
        if (lane >= off) x += y;
    }
    if (lane == 63) wsum[wid] = x;
    __syncthreads();
    int add = 0;
    for (int w = 0; w < wid; ++w) add += wsum[w];
    int incl = x + add;
    int rs = span0 + incl - v;          // global exclusive offset
    int node = nbase + tid;
    if (node < N) {
        row_start[node] = rs;
        dinv[node] = rsqrtf((float)(v + 1));   // +1 self loop
        if (node == N - 1) row_start[N] = rs + v;
    }
    cur[tid] = rs;
    __syncthreads();
    for (int i = span0 + tid; i < span1; i += 256) {
        unsigned int rec = part[i];
        int p = atomicAdd(&cur[rec >> 24], 1);
        csr_src[p] = (int)(rec & 0xFFFFFFu);
    }
}

// ---------------- layer 1 linear: 128 -> 8, LDS-tiled; fp16 out ----------------
#define TN 64
__global__ void k_lin1(const float* __restrict__ x, const float* __restrict__ W,
                       const float* __restrict__ dinv,
                       __half* __restrict__ hs, int n) {
    __shared__ float xs[TN * 132];
    __shared__ float ws[128 * 8];
    int tid = threadIdx.x;
    int base = blockIdx.x * TN;
    for (int i = tid; i < 1024; i += 256) ws[i] = W[i];
    int nvalid = n - base; if (nvalid > TN) nvalid = TN;
    int limit4 = nvalid * 32;
    const float4* x4 = (const float4*)(x + (size_t)base * 128);
    float4* xs4 = (float4*)xs;
    for (int i = tid; i < TN * 32; i += 256) {
        if (i < limit4) {
            int row = i >> 5, col = i & 31;
            xs4[row * 33 + col] = x4[i];
        }
    }
    __syncthreads();
    #pragma unroll
    for (int rep = 0; rep < 2; ++rep) {
        int o = rep * 256 + tid;
        int node = o >> 3, feat = o & 7;
        if (node < nvalid) {
            const float* xr = xs + node * 132;
            float s = 0.f;
            #pragma unroll 8
            for (int k = 0; k < 128; ++k) s = fmaf(xr[k], ws[k * 8 + feat], s);
            s *= dinv[base + node];
            // 64 consecutive lanes write 64 consecutive halves -> coalesced 128B/wave
            hs[(size_t)(base + node) * 8 + feat] = __float2half(s);
        }
    }
}

// ---------------- CSR gather (fp16 rows, fp32 accum) + fused BN-stats ------------
// P = F/8 threads per node; each thread owns 8 features = one 16B row chunk.
template<int F>
__global__ void k_gather(const int* __restrict__ row_start, const int* __restrict__ csr_src,
                         const float4* __restrict__ hp, const float* __restrict__ dinv,
                         float* __restrict__ acc, float* __restrict__ S, int n) {
    constexpr int P = F / 8;
    __shared__ float ls[2 * F];
    if (threadIdx.x < 2 * F) ls[threadIdx.x] = 0.f;
    __syncthreads();

    int t = blockIdx.x * blockDim.x + threadIdx.x;
    int node = (P == 1) ? t : (t >> 1);
    int part = (P == 1) ? 0 : (t & 1);

    float af[8];
    #pragma unroll
    for (int j = 0; j < 8; ++j) af[j] = 0.f;
    float di = 0.f;

    if (node < n) {
        // self-loop term
        {
            float4 r = hp[(size_t)node * P + part];
            const __half2* h = (const __half2*)&r;
            #pragma unroll
            for (int q = 0; q < 4; ++q) {
                float2 f = __half22float2(h[q]);
                af[2*q] += f.x; af[2*q+1] += f.y;
            }
        }
        int e = row_start[node], end = row_start[node + 1];
        for (; e + 1 < end; e += 2) {            // 2-way unroll for MLP
            int s0 = csr_src[e], s1 = csr_src[e + 1];
            float4 r0 = hp[(size_t)s0 * P + part];
            float4 r1 = hp[(size_t)s1 * P + part];
            const __half2* h0 = (const __half2*)&r0;
            const __half2* h1 = (const __half2*)&r1;
            #pragma unroll
            for (int q = 0; q < 4; ++q) {
                float2 f0 = __half22float2(h0[q]);
                float2 f1 = __half22float2(h1[q]);
                af[2*q]   += f0.x + f1.x;
                af[2*q+1] += f0.y + f1.y;
            }
        }
        if (e < end) {
            int s0 = csr_src[e];
            float4 r0 = hp[(size_t)s0 * P + part];
            const __half2* h0 = (const __half2*)&r0;
            #pragma unroll
            for (int q = 0; q < 4; ++q) {
                float2 f0 = __half22float2(h0[q]);
                af[2*q] += f0.x; af[2*q+1] += f0.y;
            }
        }
        float4* ap = (float4*)(acc + (size_t)node * F + part * 8);
        float4 o0, o1;
        o0.x = af[0]; o0.y = af[1]; o0.z = af[2]; o0.w = af[3];
        o1.x = af[4]; o1.y = af[5]; o1.z = af[6]; o1.w = af[7];
        ap[0] = o0; ap[1] = o1;
        di = dinv[node];
    }

    // BN stats on v = af*di (zeros for padding threads)
    float s1v[8], s2v[8];
    #pragma unroll
    for (int j = 0; j < 8; ++j) {
        float v = af[j] * di;
        s1v[j] = v; s2v[j] = v * v;
    }
    #pragma unroll
    for (int j = 0; j < 8; ++j) {
        #pragma unroll
        for (int off = P; off < 64; off <<= 1) {
            s1v[j] += __shfl_down(s1v[j], off);
            s2v[j] += __shfl_down(s2v[j], off);
        }
    }
    int lane = threadIdx.x & 63;
    if (lane < P) {
        int j0 = part * 8;
        #pragma unroll
        for (int j = 0; j < 8; ++j) {
            atomicAdd(&ls[j0 + j], s1v[j]);
            atomicAdd(&ls[F + j0 + j], s2v[j]);
        }
    }
    __syncthreads();
    if (threadIdx.x < 2 * F) atomicAdd(&S[threadIdx.x], ls[threadIdx.x]);
}

// ---------------- fused BN + ReLU + next linear; fp16 out ----------------
template<int FIN, int FOUT>
__global__ void k_bnlin(const float* __restrict__ acc, const float* __restrict__ dinv,
                        const float* __restrict__ S,
                        const float* __restrict__ g, const float* __restrict__ be,
                        const float* __restrict__ W,
                        __half* __restrict__ hs, int n) {
    __shared__ float sc[FIN], sh[FIN], ws[FIN * FOUT];
    int tid = threadIdx.x;
    if (tid < FIN) {
        float mu = S[tid] / (float)n;
        float var = S[FIN + tid] / (float)n - mu * mu;
        float inv = rsqrtf(var + EPS) * g[tid];
        sc[tid] = inv;
        sh[tid] = be[tid] - mu * inv;
    }
    for (int i = tid; i < FIN * FOUT; i += blockDim.x) ws[i] = W[i];
    __syncthreads();
    int i = blockIdx.x * blockDim.x + tid;
    if (i >= n) return;
    float di = dinv[i];
    float xr[FIN];
    const float4* ap = (const float4*)(acc + (size_t)i * FIN);
    #pragma unroll
    for (int q = 0; q < FIN / 4; ++q) {
        float4 a = ap[q];
        xr[4*q+0] = fmaxf(fmaf(a.x * di, sc[4*q+0], sh[4*q+0]), 0.f);
        xr[4*q+1] = fmaxf(fmaf(a.y * di, sc[4*q+1], sh[4*q+1]), 0.f);
        xr[4*q+2] = fmaxf(fmaf(a.z * di, sc[4*q+2], sh[4*q+2]), 0.f);
        xr[4*q+3] = fmaxf(fmaf(a.w * di, sc[4*q+3], sh[4*q+3]), 0.f);
    }
    float out[FOUT];
    #pragma unroll
    for (int j = 0; j < FOUT; ++j) {
        float s = 0.f;
        #pragma unroll
        for (int k = 0; k < FIN; ++k) s = fmaf(xr[k], ws[k * FOUT + j], s);
        out[j] = s * di;
    }
    // pack to fp16, store as 16B chunks
    float4 pk[FOUT / 8];
    __half2* ph = (__half2*)pk;
    #pragma unroll
    for (int j = 0; j < FOUT / 2; ++j)
        ph[j] = __floats2half2_rn(out[2*j], out[2*j+1]);
    float4* hp = (float4*)(hs + (size_t)i * FOUT);
    #pragma unroll
    for (int q = 0; q < FOUT / 8; ++q) hp[q] = pk[q];
}

// ---------------- final layer: BN + ReLU + per-block max (no atomics) ------------
__global__ void k_bnmax(const float* __restrict__ acc, const float* __restrict__ dinv,
                        const float* __restrict__ S,
                        const float* __restrict__ g, const float* __restrict__ be,
                        float* __restrict__ bmax, int n) {
    __shared__ float sc[8], sh[8];
    __shared__ float wmax[4 * 8];
    int tid = threadIdx.x;
    if (tid < 8) {
        float mu = S[tid] / (float)n;
        float var = S[8 + tid] / (float)n - mu * mu;
        float inv = rsqrtf(var + EPS) * g[tid];
        sc[tid] = inv;
        sh[tid] = be[tid] - mu * inv;
    }
    __syncthreads();
    int i = blockIdx.x * blockDim.x + tid;
    float vals[8];
    #pragma unroll
    for (int j = 0; j < 8; ++j) vals[j] = 0.f;
    if (i < n) {
        float di = dinv[i];
        const float4* ap = (const float4*)(acc + (size_t)i * 8);
        #pragma unroll
        for (int q = 0; q < 2; ++q) {
            float4 a = ap[q];
            vals[4*q+0] = fmaxf(fmaf(a.x * di, sc[4*q+0], sh[4*q+0]), 0.f);
            vals[4*q+1] = fmaxf(fmaf(a.y * di, sc[4*q+1], sh[4*q+1]), 0.f);
            vals[4*q+2] = fmaxf(fmaf(a.z * di, sc[4*q+2], sh[4*q+2]), 0.f);
            vals[4*q+3] = fmaxf(fmaf(a.w * di, sc[4*q+3], sh[4*q+3]), 0.f);
        }
    }
    #pragma unroll
    for (int j = 0; j < 8; ++j) {
        #pragma unroll
        for (int off = 32; off > 0; off >>= 1)
            vals[j] = fmaxf(vals[j], __shfl_down(vals[j], off));
    }
    int lane = tid & 63, wid = tid >> 6;
    if (lane == 0) {
        #pragma unroll
        for (int j = 0; j < 8; ++j) wmax[wid * 8 + j] = vals[j];
    }
    __syncthreads();
    if (tid < 8) {
        float m = wmax[tid];
        #pragma unroll
        for (int w = 1; w < 4; ++w) m = fmaxf(m, wmax[w * 8 + tid]);
        bmax[blockIdx.x * 8 + tid] = m;
    }
}

// ---------------- final: reduce per-block maxima, dot with Wout ----------------
__global__ void k_final(const float* __restrict__ bmax, const float* __restrict__ Wout,
                        const float* __restrict__ bout, float* __restrict__ out, int nb) {
    __shared__ float red[64 * 8];
    int tid = threadIdx.x;            // 512 threads: (chunk c, feature j)
    int j = tid & 7, c = tid >> 3;
    float m = 0.f;
    for (int b = c; b < nb; b += 64) m = fmaxf(m, bmax[b * 8 + j]);
    red[c * 8 + j] = m;
    __syncthreads();
    if (tid < 8) {
        float mm = red[tid];
        for (int cc = 1; cc < 64; ++cc) mm = fmaxf(mm, red[cc * 8 + tid]);
        red[tid] = mm;
    }
    __syncthreads();
    if (tid == 0) {
        float s = bout[0];
        #pragma unroll
        for (int k = 0; k < 8; ++k) s = fmaf(red[k], Wout[k], s);
        out[0] = s;
    }
}

extern "C" void kernel_launch(void* const* d_in, const int* in_sizes, int n_in,
                              void* d_out, int out_size, void* d_ws, size_t ws_size,
                              hipStream_t stream) {
    const float* x    = (const float*)d_in[0];
    const int*   ei   = (const int*)d_in[1];
    const float* W1   = (const float*)d_in[2];
    const float* g1   = (const float*)d_in[4];
    const float* be1  = (const float*)d_in[5];
    const float* W2   = (const float*)d_in[6];
    const float* g2   = (const float*)d_in[8];
    const float* be2  = (const float*)d_in[9];
    const float* W3   = (const float*)d_in[10];
    const float* g3   = (const float*)d_in[12];
    const float* be3  = (const float*)d_in[13];
    const float* W4   = (const float*)d_in[14];
    const float* g4   = (const float*)d_in[16];
    const float* be4  = (const float*)d_in[17];
    const float* Wout = (const float*)d_in[18];
    const float* bout = (const float*)d_in[19];
    float* out = (float*)d_out;

    const int N = in_sizes[0] / 128;
    const int E = in_sizes[1] / 2;
    const int* src = ei;
    const int* dst = ei + E;
    const int nbk = (N + 255) >> 8;              // 256-node buckets (391)
    const int gT  = (E + TILE - 1) / TILE;       // partition blocks (98)

    // workspace layout
    char* ws = (char*)d_ws;
    size_t o = 0;
    float* dinv      = (float*)(ws + o); o += 4 * (size_t)N;
    int*   row_start = (int*)(ws + o);   o += 4 * ((size_t)N + 16);
    float* stats     = (float*)(ws + o); o += 4096;
    int*   cells     = (int*)(ws + o);   o += 4 * (size_t)((nbk + 1) * gT + 64);
    float* bmax      = (float*)(ws + o); o += 4 * (size_t)(((N + 255) / 256) * 8 + 64);
    // hs (fp16, max 32B/node) + acc (fp32, max 64B/node); 'part' aliases this region
    size_t hsacc = 96 * (size_t)N;
    if ((size_t)4 * E > hsacc) hsacc = (size_t)4 * E;
    __half* hs       = (__half*)(ws + o);
    float*  acc      = (float*)(ws + o + 32 * (size_t)N);
    unsigned int* part = (unsigned int*)(ws + o);   // dead before k_lin1
    o += hsacc;
    int*   csr_src   = (int*)(ws + o);   o += 4 * (size_t)E;

    const int B = 256;
    int gN  = (N + B - 1) / B;
    int gN2 = (2 * N + B - 1) / B;

    // ---- graph prep: per-block hist -> scan -> atomic-free partition -> fill ----
    k_init<<<1, 256, 0, stream>>>(stats);
    k_hist2d<<<gT, B, 0, stream>>>(dst, cells, E, nbk, gT);
    k_scan1b<<<1, 1024, 0, stream>>>(cells, nbk * gT);
    k_part2<<<gT, B, 0, stream>>>(src, dst, cells, part, E, nbk, gT);
    k_fill2<<<nbk, B, 0, stream>>>(part, cells, dinv, row_start, csr_src, N, E, nbk, gT);

    // ---- layer 1: 128 -> 8 ----
    k_lin1<<<(N + TN - 1) / TN, B, 0, stream>>>(x, W1, dinv, hs, N);
    k_gather<8><<<gN, B, 0, stream>>>(row_start, csr_src, (const float4*)hs, dinv, acc, stats + 0, N);

    // ---- layer 2: 8 -> 16 ----
    k_bnlin<8, 16><<<gN, B, 0, stream>>>(acc, dinv, stats + 0, g1, be1, W2, hs, N);
    k_gather<16><<<gN2, B, 0, stream>>>(row_start, csr_src, (const float4*)hs, dinv, acc, stats + 32, N);

    // ---- layer 3: 16 -> 16 ----
    k_bnlin<16, 16><<<gN, B, 0, stream>>>(acc, dinv, stats + 32, g2, be2, W3, hs, N);
    k_gather<16><<<gN2, B, 0, stream>>>(row_start, csr_src, (const float4*)hs, dinv, acc, stats + 64, N);

    // ---- layer 4: 16 -> 8 ----
    k_bnlin<16, 8><<<gN, B, 0, stream>>>(acc, dinv, stats + 64, g3, be3, W4, hs, N);
    k_gather<8><<<gN, B, 0, stream>>>(row_start, csr_src, (const float4*)hs, dinv, acc, stats + 96, N);

    // ---- BN + ReLU + max-pool + output ----
    k_bnmax<<<gN, B, 0, stream>>>(acc, dinv, stats + 96, g4, be4, bmax, N);
    k_final<<<1, 512, 0, stream>>>(bmax, Wout, bout, out, gN);
}

// Round 6
// 405.495 us; speedup vs baseline: 9.4729x; 1.2012x over previous
//
#include <hip/hip_runtime.h>
#include <hip/hip_fp16.h>
#include <cstddef>

#define EPS 1e-5f
#define TILE 4096   // edges per partition block (16 per thread, block=256)

// ---------------- init: zero stats + bucket histogram ----------------
__global__ void k_init(float* __restrict__ stats, int* __restrict__ bhist) {
    int t = threadIdx.x;            // single block of 512
    if (t < 256) stats[t] = 0.f;    // 4 layers x (S1+S2) blocks of 32 floats
    bhist[t] = 0;                   // 512 >= nbk
}

// ---------------- coarse bucket histogram (dst >> 8), LDS-aggregated ----------------
__global__ void k_bhist(const int* __restrict__ dst, int* __restrict__ bhist,
                        int E, int nbk) {
    __shared__ int hist[512];
    int tid = threadIdx.x;
    int tile0 = blockIdx.x * TILE;
    for (int i = tid; i < nbk; i += 256) hist[i] = 0;
    __syncthreads();
    #pragma unroll
    for (int k = 0; k < 16; ++k) {
        int e = tile0 + k * 256 + tid;
        if (e < E) atomicAdd(&hist[dst[e] >> 8], 1);
    }
    __syncthreads();
    for (int i = tid; i < nbk; i += 256) {
        int c = hist[i];
        if (c) atomicAdd(&bhist[i], c);
    }
}

// ---------------- scan bucket counts -> bucket offsets (1 block of 512) ----------------
__global__ void k_bscan(const int* __restrict__ bhist, int* __restrict__ bcur,
                        int* __restrict__ bstart, int nbk, int E) {
    __shared__ int tmp[512];
    int t = threadIdx.x;
    int v = (t < nbk) ? bhist[t] : 0;
    tmp[t] = v;
    __syncthreads();
    for (int off = 1; off < 512; off <<= 1) {
        int y = (t >= off) ? tmp[t - off] : 0;
        __syncthreads();
        tmp[t] += y;
        __syncthreads();
    }
    if (t < nbk) { int ex = tmp[t] - v; bcur[t] = ex; bstart[t] = ex; }
    if (t == 0) bstart[nbk] = E;
}

// ---------------- partition: edges -> buckets, packed (dlocal<<24)|src ----------------
// Register-cached records; per-block base claiming via LDS-aggregated global atomics.
__global__ void k_part(const int* __restrict__ src, const int* __restrict__ dst,
                       int* __restrict__ bcur, unsigned int* __restrict__ part,
                       int E, int nbk) {
    __shared__ int hist[512];
    __shared__ int base[512];
    int tid = threadIdx.x;
    int tile0 = blockIdx.x * TILE;
    for (int i = tid; i < nbk; i += 256) hist[i] = 0;
    __syncthreads();
    unsigned int rec[16];
    int bk[16];
    #pragma unroll
    for (int k = 0; k < 16; ++k) {
        int e = tile0 + k * 256 + tid;
        bk[k] = -1;
        if (e < E) {
            int d = dst[e], s = src[e];
            bk[k] = d >> 8;
            rec[k] = ((unsigned int)(d & 255) << 24) | (unsigned int)s;
            atomicAdd(&hist[bk[k]], 1);
        }
    }
    __syncthreads();
    for (int i = tid; i < nbk; i += 256) {
        int c = hist[i];
        base[i] = c ? atomicAdd(&bcur[i], c) : 0;
        hist[i] = 0;
    }
    __syncthreads();
    #pragma unroll
    for (int k = 0; k < 16; ++k) {
        if (bk[k] >= 0) {
            int r = atomicAdd(&hist[bk[k]], 1);
            part[base[bk[k]] + r] = rec[k];
        }
    }
}

// ---------------- per-bucket: degrees -> row_start + dinv, then csr fill ----------
// 512 threads/block for latency hiding; nodes handled by tid<256.
__global__ void k_fill2(const unsigned int* __restrict__ part, const int* __restrict__ bstart,
                        float* __restrict__ dinv, int* __restrict__ row_start,
                        int* __restrict__ csr_src, int N) {
    __shared__ int hist[256];
    __shared__ int cur[256];
    __shared__ int wsum[8];
    int b = blockIdx.x, tid = threadIdx.x;
    int nbase = b << 8;
    int span0 = bstart[b], span1 = bstart[b + 1];
    if (tid < 256) hist[tid] = 0;
    __syncthreads();
    for (int i = span0 + tid; i < span1; i += 512)
        atomicAdd(&hist[part[i] >> 24], 1);
    __syncthreads();
    int v = (tid < 256) ? hist[tid] : 0;
    int lane = tid & 63, wid = tid >> 6;
    int x = v;
    #pragma unroll
    for (int off = 1; off < 64; off <<= 1) {
        int y = __shfl_up(x, off);
        if (lane >= off) x += y;
    }
    if (lane == 63) wsum[wid] = x;
    __syncthreads();
    int add = 0;
    for (int w = 0; w < wid && w < 4; ++w) add += wsum[w];
    int incl = x + add;
    int rs = span0 + incl - v;          // global exclusive offset (valid for tid<256)
    int node = nbase + tid;
    if (tid < 256 && node < N) {
        row_start[node] = rs;
        dinv[node] = rsqrtf((float)(v + 1));   // +1 self loop
        if (node == N - 1) row_start[N] = rs + v;
    }
    if (tid < 256) cur[tid] = rs;
    __syncthreads();
    for (int i = span0 + tid; i < span1; i += 512) {
        unsigned int rec = part[i];
        int p = atomicAdd(&cur[rec >> 24], 1);
        csr_src[p] = (int)(rec & 0xFFFFFFu);
    }
}

// ---------------- layer 1 linear: 128 -> 8, LDS-tiled; fp16 out ----------------
#define TN 64
__global__ void k_lin1(const float* __restrict__ x, const float* __restrict__ W,
                       const float* __restrict__ dinv,
                       __half* __restrict__ hs, int n) {
    __shared__ float xs[TN * 132];
    __shared__ float ws[128 * 8];
    int tid = threadIdx.x;
    int base = blockIdx.x * TN;
    for (int i = tid; i < 1024; i += 256) ws[i] = W[i];
    int nvalid = n - base; if (nvalid > TN) nvalid = TN;
    int limit4 = nvalid * 32;
    const float4* x4 = (const float4*)(x + (size_t)base * 128);
    float4* xs4 = (float4*)xs;
    for (int i = tid; i < TN * 32; i += 256) {
        if (i < limit4) {
            int row = i >> 5, col = i & 31;
            xs4[row * 33 + col] = x4[i];
        }
    }
    __syncthreads();
    #pragma unroll
    for (int rep = 0; rep < 2; ++rep) {
        int o = rep * 256 + tid;
        int node = o >> 3, feat = o & 7;
        if (node < nvalid) {
            const float* xr = xs + node * 132;
            float s = 0.f;
            #pragma unroll 8
            for (int k = 0; k < 128; ++k) s = fmaf(xr[k], ws[k * 8 + feat], s);
            s *= dinv[base + node];
            hs[(size_t)(base + node) * 8 + feat] = __float2half(s);
        }
    }
}

// ---------------- CSR gather (fp16 rows, fp32 accum) + fused BN-stats ------------
// P = F/8 threads per node; each thread owns 8 features = one 16B row chunk.
template<int F>
__global__ void k_gather(const int* __restrict__ row_start, const int* __restrict__ csr_src,
                         const float4* __restrict__ hp, const float* __restrict__ dinv,
                         float* __restrict__ acc, float* __restrict__ S, int n) {
    constexpr int P = F / 8;
    __shared__ float ls[2 * F];
    if (threadIdx.x < 2 * F) ls[threadIdx.x] = 0.f;
    __syncthreads();

    int t = blockIdx.x * blockDim.x + threadIdx.x;
    int node = (P == 1) ? t : (t >> 1);
    int part = (P == 1) ? 0 : (t & 1);

    float af[8];
    #pragma unroll
    for (int j = 0; j < 8; ++j) af[j] = 0.f;
    float di = 0.f;

    if (node < n) {
        {
            float4 r = hp[(size_t)node * P + part];
            const __half2* h = (const __half2*)&r;
            #pragma unroll
            for (int q = 0; q < 4; ++q) {
                float2 f = __half22float2(h[q]);
                af[2*q] += f.x; af[2*q+1] += f.y;
            }
        }
        int e = row_start[node], end = row_start[node + 1];
        for (; e + 1 < end; e += 2) {
            int s0 = csr_src[e], s1 = csr_src[e + 1];
            float4 r0 = hp[(size_t)s0 * P + part];
            float4 r1 = hp[(size_t)s1 * P + part];
            const __half2* h0 = (const __half2*)&r0;
            const __half2* h1 = (const __half2*)&r1;
            #pragma unroll
            for (int q = 0; q < 4; ++q) {
                float2 f0 = __half22float2(h0[q]);
                float2 f1 = __half22float2(h1[q]);
                af[2*q]   += f0.x + f1.x;
                af[2*q+1] += f0.y + f1.y;
            }
        }
        if (e < end) {
            int s0 = csr_src[e];
            float4 r0 = hp[(size_t)s0 * P + part];
            const __half2* h0 = (const __half2*)&r0;
            #pragma unroll
            for (int q = 0; q < 4; ++q) {
                float2 f0 = __half22float2(h0[q]);
                af[2*q] += f0.x; af[2*q+1] += f0.y;
            }
        }
        float4* ap = (float4*)(acc + (size_t)node * F + part * 8);
        float4 o0, o1;
        o0.x = af[0]; o0.y = af[1]; o0.z = af[2]; o0.w = af[3];
        o1.x = af[4]; o1.y = af[5]; o1.z = af[6]; o1.w = af[7];
        ap[0] = o0; ap[1] = o1;
        di = dinv[node];
    }

    float s1v[8], s2v[8];
    #pragma unroll
    for (int j = 0; j < 8; ++j) {
        float v = af[j] * di;
        s1v[j] = v; s2v[j] = v * v;
    }
    #pragma unroll
    for (int j = 0; j < 8; ++j) {
        #pragma unroll
        for (int off = P; off < 64; off <<= 1) {
            s1v[j] += __shfl_down(s1v[j], off);
            s2v[j] += __shfl_down(s2v[j], off);
        }
    }
    int lane = threadIdx.x & 63;
    if (lane < P) {
        int j0 = part * 8;
        #pragma unroll
        for (int j = 0; j < 8; ++j) {
            atomicAdd(&ls[j0 + j], s1v[j]);
            atomicAdd(&ls[F + j0 + j], s2v[j]);
        }
    }
    __syncthreads();
    if (threadIdx.x < 2 * F) atomicAdd(&S[threadIdx.x], ls[threadIdx.x]);
}

// ---------------- fused BN + ReLU + next linear; fp16 out ----------------
template<int FIN, int FOUT>
__global__ void k_bnlin(const float* __restrict__ acc, const float* __restrict__ dinv,
                        const float* __restrict__ S,
                        const float* __restrict__ g, const float* __restrict__ be,
                        const float* __restrict__ W,
                        __half* __restrict__ hs, int n) {
    __shared__ float sc[FIN], sh[FIN], ws[FIN * FOUT];
    int tid = threadIdx.x;
    if (tid < FIN) {
        float mu = S[tid] / (float)n;
        float var = S[FIN + tid] / (float)n - mu * mu;
        float inv = rsqrtf(var + EPS) * g[tid];
        sc[tid] = inv;
        sh[tid] = be[tid] - mu * inv;
    }
    for (int i = tid; i < FIN * FOUT; i += blockDim.x) ws[i] = W[i];
    __syncthreads();
    int i = blockIdx.x * blockDim.x + tid;
    if (i >= n) return;
    float di = dinv[i];
    float xr[FIN];
    const float4* ap = (const float4*)(acc + (size_t)i * FIN);
    #pragma unroll
    for (int q = 0; q < FIN / 4; ++q) {
        float4 a = ap[q];
        xr[4*q+0] = fmaxf(fmaf(a.x * di, sc[4*q+0], sh[4*q+0]), 0.f);
        xr[4*q+1] = fmaxf(fmaf(a.y * di, sc[4*q+1], sh[4*q+1]), 0.f);
        xr[4*q+2] = fmaxf(fmaf(a.z * di, sc[4*q+2], sh[4*q+2]), 0.f);
        xr[4*q+3] = fmaxf(fmaf(a.w * di, sc[4*q+3], sh[4*q+3]), 0.f);
    }
    float out[FOUT];
    #pragma unroll
    for (int j = 0; j < FOUT; ++j) {
        float s = 0.f;
        #pragma unroll
        for (int k = 0; k < FIN; ++k) s = fmaf(xr[k], ws[k * FOUT + j], s);
        out[j] = s * di;
    }
    float4 pk[FOUT / 8];
    __half2* ph = (__half2*)pk;
    #pragma unroll
    for (int j = 0; j < FOUT / 2; ++j)
        ph[j] = __floats2half2_rn(out[2*j], out[2*j+1]);
    float4* hp = (float4*)(hs + (size_t)i * FOUT);
    #pragma unroll
    for (int q = 0; q < FOUT / 8; ++q) hp[q] = pk[q];
}

// ---------------- final layer: BN + ReLU + per-block max (no atomics) ------------
__global__ void k_bnmax(const float* __restrict__ acc, const float* __restrict__ dinv,
                        const float* __restrict__ S,
                        const float* __restrict__ g, const float* __restrict__ be,
                        float* __restrict__ bmax, int n) {
    __shared__ float sc[8], sh[8];
    __shared__ float wmax[4 * 8];
    int tid = threadIdx.x;
    if (tid < 8) {
        float mu = S[tid] / (float)n;
        float var = S[8 + tid] / (float)n - mu * mu;
        float inv = rsqrtf(var + EPS) * g[tid];
        sc[tid] = inv;
        sh[tid] = be[tid] - mu * inv;
    }
    __syncthreads();
    int i = blockIdx.x * blockDim.x + tid;
    float vals[8];
    #pragma unroll
    for (int j = 0; j < 8; ++j) vals[j] = 0.f;
    if (i < n) {
        float di = dinv[i];
        const float4* ap = (const float4*)(acc + (size_t)i * 8);
        #pragma unroll
        for (int q = 0; q < 2; ++q) {
            float4 a = ap[q];
            vals[4*q+0] = fmaxf(fmaf(a.x * di, sc[4*q+0], sh[4*q+0]), 0.f);
            vals[4*q+1] = fmaxf(fmaf(a.y * di, sc[4*q+1], sh[4*q+1]), 0.f);
            vals[4*q+2] = fmaxf(fmaf(a.z * di, sc[4*q+2], sh[4*q+2]), 0.f);
            vals[4*q+3] = fmaxf(fmaf(a.w * di, sc[4*q+3], sh[4*q+3]), 0.f);
        }
    }
    #pragma unroll
    for (int j = 0; j < 8; ++j) {
        #pragma unroll
        for (int off = 32; off > 0; off >>= 1)
            vals[j] = fmaxf(vals[j], __shfl_down(vals[j], off));
    }
    int lane = tid & 63, wid = tid >> 6;
    if (lane == 0) {
        #pragma unroll
        for (int j = 0; j < 8; ++j) wmax[wid * 8 + j] = vals[j];
    }
    __syncthreads();
    if (tid < 8) {
        float m = wmax[tid];
        #pragma unroll
        for (int w = 1; w < 4; ++w) m = fmaxf(m, wmax[w * 8 + tid]);
        bmax[blockIdx.x * 8 + tid] = m;
    }
}

// ---------------- final: reduce per-block maxima, dot with Wout ----------------
__global__ void k_final(const float* __restrict__ bmax, const float* __restrict__ Wout,
                        const float* __restrict__ bout, float* __restrict__ out, int nb) {
    __shared__ float red[64 * 8];
    int tid = threadIdx.x;            // 512 threads: (chunk c, feature j)
    int j = tid & 7, c = tid >> 3;
    float m = 0.f;
    for (int b = c; b < nb; b += 64) m = fmaxf(m, bmax[b * 8 + j]);
    red[c * 8 + j] = m;
    __syncthreads();
    if (tid < 8) {
        float mm = red[tid];
        for (int cc = 1; cc < 64; ++cc) mm = fmaxf(mm, red[cc * 8 + tid]);
        red[tid] = mm;
    }
    __syncthreads();
    if (tid == 0) {
        float s = bout[0];
        #pragma unroll
        for (int k = 0; k < 8; ++k) s = fmaf(red[k], Wout[k], s);
        out[0] = s;
    }
}

extern "C" void kernel_launch(void* const* d_in, const int* in_sizes, int n_in,
                              void* d_out, int out_size, void* d_ws, size_t ws_size,
                              hipStream_t stream) {
    const float* x    = (const float*)d_in[0];
    const int*   ei   = (const int*)d_in[1];
    const float* W1   = (const float*)d_in[2];
    const float* g1   = (const float*)d_in[4];
    const float* be1  = (const float*)d_in[5];
    const float* W2   = (const float*)d_in[6];
    const float* g2   = (const float*)d_in[8];
    const float* be2  = (const float*)d_in[9];
    const float* W3   = (const float*)d_in[10];
    const float* g3   = (const float*)d_in[12];
    const float* be3  = (const float*)d_in[13];
    const float* W4   = (const float*)d_in[14];
    const float* g4   = (const float*)d_in[16];
    const float* be4  = (const float*)d_in[17];
    const float* Wout = (const float*)d_in[18];
    const float* bout = (const float*)d_in[19];
    float* out = (float*)d_out;

    const int N = in_sizes[0] / 128;
    const int E = in_sizes[1] / 2;
    const int* src = ei;
    const int* dst = ei + E;
    const int nbk = (N + 255) >> 8;              // 256-node buckets (391)
    const int gT  = (E + TILE - 1) / TILE;       // partition blocks (782)

    // workspace layout
    char* ws = (char*)d_ws;
    size_t o = 0;
    float* dinv      = (float*)(ws + o); o += 4 * (size_t)N;
    int*   row_start = (int*)(ws + o);   o += 4 * ((size_t)N + 16);
    float* stats     = (float*)(ws + o); o += 4096;
    int*   bhist     = (int*)(ws + o);   o += 2048;
    int*   bcur      = (int*)(ws + o);   o += 2048;
    int*   bstart    = (int*)(ws + o);   o += 4096;
    float* bmax      = (float*)(ws + o); o += 4 * (size_t)(((N + 255) / 256) * 8 + 64);
    // hs (fp16, max 32B/node) + acc (fp32, max 64B/node); 'part' aliases this region
    size_t hsacc = 96 * (size_t)N;
    if ((size_t)4 * E > hsacc) hsacc = (size_t)4 * E;
    __half* hs       = (__half*)(ws + o);
    float*  acc      = (float*)(ws + o + 32 * (size_t)N);
    unsigned int* part = (unsigned int*)(ws + o);   // dead before k_lin1
    o += hsacc;
    int*   csr_src   = (int*)(ws + o);   o += 4 * (size_t)E;

    const int B = 256;
    int gN  = (N + B - 1) / B;
    int gN2 = (2 * N + B - 1) / B;

    // ---- graph prep: bucket hist -> scan -> partition -> per-bucket fill ----
    k_init<<<1, 512, 0, stream>>>(stats, bhist);
    k_bhist<<<gT, B, 0, stream>>>(dst, bhist, E, nbk);
    k_bscan<<<1, 512, 0, stream>>>(bhist, bcur, bstart, nbk, E);
    k_part<<<gT, B, 0, stream>>>(src, dst, bcur, part, E, nbk);
    k_fill2<<<nbk, 512, 0, stream>>>(part, bstart, dinv, row_start, csr_src, N);

    // ---- layer 1: 128 -> 8 ----
    k_lin1<<<(N + TN - 1) / TN, B, 0, stream>>>(x, W1, dinv, hs, N);
    k_gather<8><<<gN, B, 0, stream>>>(row_start, csr_src, (const float4*)hs, dinv, acc, stats + 0, N);

    // ---- layer 2: 8 -> 16 ----
    k_bnlin<8, 16><<<gN, B, 0, stream>>>(acc, dinv, stats + 0, g1, be1, W2, hs, N);
    k_gather<16><<<gN2, B, 0, stream>>>(row_start, csr_src, (const float4*)hs, dinv, acc, stats + 32, N);

    // ---- layer 3: 16 -> 16 ----
    k_bnlin<16, 16><<<gN, B, 0, stream>>>(acc, dinv, stats + 32, g2, be2, W3, hs, N);
    k_gather<16><<<gN2, B, 0, stream>>>(row_start, csr_src, (const float4*)hs, dinv, acc, stats + 64, N);

    // ---- layer 4: 16 -> 8 ----
    k_bnlin<16, 8><<<gN, B, 0, stream>>>(acc, dinv, stats + 64, g3, be3, W4, hs, N);
    k_gather<8><<<gN, B, 0, stream>>>(row_start, csr_src, (const float4*)hs, dinv, acc, stats + 96, N);

    // ---- BN + ReLU + max-pool + output ----
    k_bnmax<<<gN, B, 0, stream>>>(acc, dinv, stats + 96, g4, be4, bmax, N);
    k_final<<<1, 512, 0, stream>>>(bmax, Wout, bout, out, gN);
}